// Round 20
// baseline (1760.943 us; speedup 1.0000x reference)
//
#include <hip/hip_runtime.h>
#include <hip/hip_bf16.h>
#include <math.h>
#include <stdint.h>

#define TOK 32768
#define DIM 1024
#define NE 8
#define NSEG 16                      /* (k, expert) segments */
#define BMCAP (2 * TOK + NSEG * 256) /* 69632 row slots (segments padded to 256) */

#define C_CNT(s) ((s) * 16)
#define C_CUR(s) (256 + (s) * 16)
#define C_SEG(s) (512 + (s))

typedef __attribute__((ext_vector_type(8))) short bf16x8;
typedef __attribute__((ext_vector_type(4))) float f32x4;
typedef unsigned short ushort_t;

__device__ __forceinline__ unsigned short f2b(float x) {
  union { float f; unsigned u; } v; v.f = x;
  unsigned r = v.u + 0x7fffu + ((v.u >> 16) & 1u);
  return (unsigned short)(r >> 16);
}

// fast gelu: logistic form of tanh-approx; |err vs erf-gelu| <= ~3e-4
__device__ __forceinline__ float gelu_fast(float x) {
  const float y2 = -1.5957691216057308f * x * fmaf(0.044715f, x * x, 1.0f);
  return x * __builtin_amdgcn_rcpf(1.0f + __expf(y2));
}

__device__ __forceinline__ void async16(void* lds, const void* g) {
  auto* lp = (__attribute__((address_space(3))) uint32_t*)lds;
  auto* gp = (__attribute__((address_space(1))) uint32_t*)(const_cast<void*>(g));
  __builtin_amdgcn_global_load_lds(gp, lp, 16, 0, 0);
}

// ---- router v3 (no atomics): FROZEN sequential fmaf chain ------------------
__global__ __launch_bounds__(256) void router_seq3(
    const float* __restrict__ tokens, const float* __restrict__ rw,
    int* __restrict__ topi, float* __restrict__ topv) {
  __shared__ float xs[2][32][132];
  __shared__ float wsh[2][8][132];
  __shared__ float sc[256];
  const int tid = threadIdx.x;
  const int e = tid & 7;
  const int tr = tid >> 3;
  const int t0 = blockIdx.x * 32;

  float4 lx0, lx1, lx2, lx3, lw;
  auto issue = [&](int c) {
    const int col = (tid & 31) * 4;
    lx0 = *(const float4*)&tokens[(size_t)(t0 + ((tid + 0) >> 5)) * DIM + c * 128 + col];
    lx1 = *(const float4*)&tokens[(size_t)(t0 + ((tid + 256) >> 5)) * DIM + c * 128 + col];
    lx2 = *(const float4*)&tokens[(size_t)(t0 + ((tid + 512) >> 5)) * DIM + c * 128 + col];
    lx3 = *(const float4*)&tokens[(size_t)(t0 + ((tid + 768) >> 5)) * DIM + c * 128 + col];
    lw  = *(const float4*)&rw[(size_t)(tid >> 5) * DIM + c * 128 + col];
  };
  auto commit = [&](int b) {
    const int col = (tid & 31) * 4;
    *(float4*)&xs[b][(tid + 0) >> 5][col] = lx0;
    *(float4*)&xs[b][(tid + 256) >> 5][col] = lx1;
    *(float4*)&xs[b][(tid + 512) >> 5][col] = lx2;
    *(float4*)&xs[b][(tid + 768) >> 5][col] = lx3;
    *(float4*)&wsh[b][tid >> 5][col] = lw;
  };

  issue(0);
  commit(0);
  __syncthreads();
  float s = 0.f;
  for (int c = 0; c < 8; c++) {
    const int b = c & 1;
    if (c + 1 < 8) issue(c + 1);
#pragma unroll
    for (int k4 = 0; k4 < 32; k4++) {
      const float4 xv = *(const float4*)&xs[b][tr][k4 * 4];
      const float4 wv = *(const float4*)&wsh[b][e][k4 * 4];
      s = fmaf(xv.x, wv.x, s);
      s = fmaf(xv.y, wv.y, s);
      s = fmaf(xv.z, wv.z, s);
      s = fmaf(xv.w, wv.w, s);
    }
    if (c + 1 < 8) commit(b ^ 1);
    __syncthreads();
  }
  sc[tid] = s;
  __syncthreads();
  if (e == 0) {
    float p[NE];
    float m = sc[tr * 8];
#pragma unroll
    for (int i = 1; i < NE; i++) m = fmaxf(m, sc[tr * 8 + i]);
    float sum = 0.f;
#pragma unroll
    for (int i = 0; i < NE; i++) {
      p[i] = expf(sc[tr * 8 + i] - m);
      sum += p[i];
    }
#pragma unroll
    for (int i = 0; i < NE; i++) p[i] = p[i] / sum;
    const int t = t0 + tr;
    int e0 = 0;
#pragma unroll
    for (int i = 1; i < NE; i++) if (p[i] > p[e0]) e0 = i;
    int e1 = (e0 == 0) ? 1 : 0;
#pragma unroll
    for (int i = 0; i < NE; i++) if (i != e0 && p[i] > p[e1]) e1 = i;
    topi[t * 2] = e0;     topv[t * 2] = p[e0];
    topi[t * 2 + 1] = e1; topv[t * 2 + 1] = p[e1];
  }
}

// ---- per-(k,expert) counts -------------------------------------------------
__global__ __launch_bounds__(256) void hist_kernel(const int* __restrict__ topi,
                                                   int* __restrict__ ctrl) {
  __shared__ int h[NSEG];
  const int tid = threadIdx.x;
  if (tid < NSEG) h[tid] = 0;
  __syncthreads();
  const int t = blockIdx.x * 256 + tid;
  atomicAdd(&h[topi[t * 2]], 1);
  atomicAdd(&h[8 + topi[t * 2 + 1]], 1);
  __syncthreads();
  if (tid < NSEG) atomicAdd(&ctrl[C_CNT(tid)], h[tid]);
}

__global__ void prefix_kernel(int* ctrl) {
  if (threadIdx.x == 0 && blockIdx.x == 0) {
    int s = 0;
    for (int g = 0; g < NSEG; g++) {
      ctrl[C_SEG(g)] = s;
      ctrl[C_CUR(g)] = s;
      s += (ctrl[C_CNT(g)] + 255) & ~255; /* pad segments to 256 (BM) */
    }
    ctrl[C_SEG(NSEG)] = s;
  }
}

__global__ __launch_bounds__(256) void init_rows(
    int* __restrict__ row_token, float* __restrict__ row_gate) {
  const int i = blockIdx.x * 256 + threadIdx.x;
  if (i < BMCAP) { row_token[i] = TOK; row_gate[i] = 0.f; }
}

__global__ __launch_bounds__(256) void assign2(
    const int* __restrict__ topi, const float* __restrict__ topv,
    int* __restrict__ ctrl, int* __restrict__ row_token,
    float* __restrict__ row_gate) {
  __shared__ int h[NSEG];
  __shared__ int base[NSEG];
  const int tid = threadIdx.x;
  const int t = blockIdx.x * 256 + tid;
  if (tid < NSEG) h[tid] = 0;
  __syncthreads();
  const int s0 = topi[t * 2], s1 = 8 + topi[t * 2 + 1];
  const int o0 = atomicAdd(&h[s0], 1);
  const int o1 = atomicAdd(&h[s1], 1);
  __syncthreads();
  if (tid < NSEG) base[tid] = atomicAdd(&ctrl[C_CUR(tid)], h[tid]);
  __syncthreads();
  const int p0 = base[s0] + o0, p1 = base[s1] + o1;
  row_token[p0] = t; row_gate[p0] = topv[t * 2];
  row_token[p1] = t; row_gate[p1] = topv[t * 2 + 1];
}

__global__ __launch_bounds__(256) void cast_tokens(
    const float* __restrict__ t, ushort_t* __restrict__ x16) {
  const size_t i = ((size_t)blockIdx.x * 256 + threadIdx.x) * 8;
  const float4 a = *(const float4*)(t + i);
  const float4 b = *(const float4*)(t + i + 4);
  bf16x8 h;
  h[0] = (short)f2b(a.x); h[1] = (short)f2b(a.y);
  h[2] = (short)f2b(a.z); h[3] = (short)f2b(a.w);
  h[4] = (short)f2b(b.x); h[5] = (short)f2b(b.y);
  h[6] = (short)f2b(b.z); h[7] = (short)f2b(b.w);
  *(bf16x8*)(x16 + i) = h;
}

__global__ __launch_bounds__(256) void transpose_cast(
    const float* __restrict__ w, ushort_t* __restrict__ wT) {
  __shared__ float tile[64][65];
  const int e = blockIdx.z;
  const int n0 = blockIdx.x * 64, k0 = blockIdx.y * 64;
  const int tx = threadIdx.x & 63, ty = threadIdx.x >> 6;
  const float* src = w + ((size_t)e << 20);
  ushort_t* dst = wT + ((size_t)e << 20);
#pragma unroll
  for (int r = ty; r < 64; r += 4)
    tile[r][tx] = src[(size_t)(k0 + r) * DIM + n0 + tx];
  __syncthreads();
#pragma unroll
  for (int r = ty; r < 64; r += 4)
    dst[(size_t)(n0 + r) * DIM + k0 + tx] = f2b(tile[tx][r]);
}

// --- grouped GEMM: 256x128 tile, BK=32, 8 waves, dbuf, 3 blocks/CU ----------
// launch_bounds(512,6): 24 waves/CU = 3 blocks resident (VGPR 64, LDS 48KB).
// Swizzle: granule ^= (row&3)^((row>>2)&3), both-sides (rule #21).
// Epilogue: 4 cross-wave rounds through 32KB scratch, coalesced wide stores.
template <int PASS, int ADD>
__global__ __launch_bounds__(512, 6) void dgemm(
    const ushort_t* __restrict__ Asrc, const ushort_t* __restrict__ Wt,
    const int* __restrict__ row_token, const float* __restrict__ row_gate,
    const int* __restrict__ ctrl, int s_lo, int s_hi, int chunk,
    ushort_t* __restrict__ Hout, float* __restrict__ out) {
  const int l = (blockIdx.x & 7) * chunk + (blockIdx.x >> 3);
  const int mt = l >> 3, nt = l & 7; // n-fastest: 8 blocks share an A-panel
  const int rbase0 = ctrl[C_SEG(s_lo)];
  const int rend = ctrl[C_SEG(s_hi)];
  const int m0 = rbase0 + mt * 256;
  if (m0 >= rend) return;
  const int n0 = nt * 128;
  int sg = s_lo;
  for (int i = s_lo + 1; i < s_hi; i++)
    if (m0 >= ctrl[C_SEG(i)]) sg = i;
  const int e = sg & 7;
  const ushort_t* B = Wt + ((size_t)e << 20);

  __shared__ __align__(16) char smem[49152];
  ushort_t (*As)[8192] = (ushort_t(*)[8192])smem;           // 2 x 16 KB
  ushort_t (*Bs)[4096] = (ushort_t(*)[4096])(smem + 32768); // 2 x 8 KB
  float* scratch = (float*)smem; // epilogue: 64x128 f32 = 32 KB

  const int tid = threadIdx.x;
  const int lane = tid & 63;
  const int wave = tid >> 6;
  const int wm = wave >> 1, wn = wave & 1; // per-wave 64x64 output
  const int lr = lane & 15;
  // read-side physical granule XOR (element offset, <<3 = *8 elems)
  const int kx = (((lane >> 4) ^ (lr & 3) ^ ((lr >> 2) & 3)) << 3);

  // staging: A rows w*32+(l>>2) (+16 for j=1), B rows w*16+(l>>2);
  // source col granule = (l&3)^((l>>2)&3)^((l>>4)&3)  (both-sides involution)
  const int ko = (((lane & 3) ^ ((lane >> 2) & 3) ^ ((lane >> 4) & 3)) << 3);
  const int ar0 = wave * 32 + (lane >> 2);
  const int brr = wave * 16 + (lane >> 2);
  const ushort_t *asrc0, *asrc1, *bsrc;
  if (PASS == 0) {
    int tk0 = row_token[m0 + ar0];
    int tk1 = row_token[m0 + ar0 + 16];
    if (tk0 >= TOK) tk0 = 0;
    if (tk1 >= TOK) tk1 = 0;
    asrc0 = Asrc + (size_t)tk0 * DIM + ko;
    asrc1 = Asrc + (size_t)tk1 * DIM + ko;
  } else {
    asrc0 = Asrc + (size_t)(m0 + ar0) * DIM + ko;
    asrc1 = Asrc + (size_t)(m0 + ar0 + 16) * DIM + ko;
  }
  bsrc = B + (size_t)(n0 + brr) * DIM + ko;

  f32x4 acc[4][4] = {};

  auto stage = [&](int b, int k0) {
    async16(&As[b][wave * 1024], asrc0 + k0);
    async16(&As[b][wave * 1024 + 512], asrc1 + k0);
    async16(&Bs[b][wave * 512], bsrc + k0);
  };
  auto compute = [&](int b) {
    bf16x8 a[4], bb[4];
#pragma unroll
    for (int mi = 0; mi < 4; mi++)
      a[mi] = *(const bf16x8*)&As[b][(wm * 64 + mi * 16 + lr) * 32 + kx];
#pragma unroll
    for (int ni = 0; ni < 4; ni++)
      bb[ni] = *(const bf16x8*)&Bs[b][(wn * 64 + ni * 16 + lr) * 32 + kx];
#pragma unroll
    for (int mi = 0; mi < 4; mi++)
#pragma unroll
      for (int ni = 0; ni < 4; ni++)
        acc[mi][ni] = __builtin_amdgcn_mfma_f32_16x16x32_bf16(
            a[mi], bb[ni], acc[mi][ni], 0, 0, 0);
  };

  stage(0, 0);
  __syncthreads();
  int cur = 0;
#pragma unroll 1
  for (int t = 0; t < 31; t++) {
    stage(cur ^ 1, (t + 1) * 32);
    compute(cur);
    __syncthreads();
    cur ^= 1;
  }
  compute(cur);
  __syncthreads(); // K-loop done; smem becomes scratch

  // ---- epilogue: 4 rounds (one 64-row m-block each) -----------------------
  const int grow = (lane >> 4) << 2;
  const int erow = tid >> 3;       // 0..63
  const int ec0 = (tid & 7) * 16;  // col base, 16 cols/thread
#pragma unroll 1
  for (int rnd = 0; rnd < 4; rnd++) {
    if (wm == rnd) {
#pragma unroll
      for (int mi = 0; mi < 4; mi++) {
#pragma unroll
        for (int ni = 0; ni < 4; ni++) {
#pragma unroll
          for (int r = 0; r < 4; r++) {
            const int lrow = mi * 16 + grow + r;
            const int lcol = (wn * 64 + ni * 16 + lr) ^ ((lrow & 3) << 2);
            scratch[lrow * 128 + lcol] = acc[mi][ni][r];
          }
        }
      }
    }
    __syncthreads();
    {
      const int q = (erow & 3) << 2;
      f32x4 v[4];
#pragma unroll
      for (int k = 0; k < 4; k++)
        v[k] = *(const f32x4*)&scratch[erow * 128 + ((ec0 + 4 * k) ^ q)];
      const int rr = m0 + rnd * 64 + erow;
      if (PASS == 0) {
        bf16x8 h0, h1;
#pragma unroll
        for (int k = 0; k < 2; k++)
#pragma unroll
          for (int j = 0; j < 4; j++)
            h0[k * 4 + j] = (short)f2b(gelu_fast(v[k][j]));
#pragma unroll
        for (int k = 0; k < 2; k++)
#pragma unroll
          for (int j = 0; j < 4; j++)
            h1[k * 4 + j] = (short)f2b(gelu_fast(v[2 + k][j]));
        *(bf16x8*)&Hout[(size_t)rr * DIM + n0 + ec0] = h0;
        *(bf16x8*)&Hout[(size_t)rr * DIM + n0 + ec0 + 8] = h1;
      } else {
        const int tok = row_token[rr];
        if (tok < TOK) {
          const float g = row_gate[rr];
          float* op = out + (size_t)tok * DIM + n0 + ec0;
#pragma unroll
          for (int k = 0; k < 4; k++) {
            f32x4 res;
            if (ADD) {
              const f32x4 old = *(const f32x4*)(op + 4 * k);
#pragma unroll
              for (int j = 0; j < 4; j++) res[j] = old[j] + g * v[k][j];
            } else {
#pragma unroll
              for (int j = 0; j < 4; j++) res[j] = g * v[k][j];
            }
            *(f32x4*)(op + 4 * k) = res;
          }
        }
      }
    }
    __syncthreads();
  }
}

extern "C" void kernel_launch(void* const* d_in, const int* in_sizes, int n_in,
                              void* d_out, int out_size, void* d_ws,
                              size_t ws_size, hipStream_t stream) {
  (void)in_sizes; (void)n_in; (void)ws_size; (void)out_size;
  const float* tokens = (const float*)d_in[0];
  const float* rw = (const float*)d_in[1];
  const float* w1 = (const float*)d_in[2];
  const float* w2 = (const float*)d_in[3];
  float* out = (float*)d_out;

  char* ws = (char*)d_ws;
  size_t off = 0;
  auto alloc = [&](size_t b) {
    size_t o = off;
    off += (b + 255) & ~(size_t)255;
    return o;
  };
  int* ctrl = (int*)(ws + alloc(4096));
  int* topi = (int*)(ws + alloc((size_t)TOK * 2 * 4));
  float* topv = (float*)(ws + alloc((size_t)TOK * 2 * 4));
  int* row_token = (int*)(ws + alloc((size_t)BMCAP * 4));
  float* row_gate = (float*)(ws + alloc((size_t)BMCAP * 4));
  ushort_t* X16 = (ushort_t*)(ws + alloc((size_t)TOK * DIM * 2));
  ushort_t* w1T = (ushort_t*)(ws + alloc((size_t)NE * DIM * DIM * 2));
  ushort_t* w2T = (ushort_t*)(ws + alloc((size_t)NE * DIM * DIM * 2));
  ushort_t* H = (ushort_t*)(ws + alloc((size_t)BMCAP * DIM * 2)); // unified

  hipMemsetAsync(ctrl, 0, 4096, stream);
  router_seq3<<<TOK / 32, 256, 0, stream>>>(tokens, rw, topi, topv);
  hist_kernel<<<TOK / 256, 256, 0, stream>>>(topi, ctrl);
  prefix_kernel<<<1, 64, 0, stream>>>(ctrl);
  init_rows<<<BMCAP / 256, 256, 0, stream>>>(row_token, row_gate);
  assign2<<<TOK / 256, 256, 0, stream>>>(topi, topv, ctrl, row_token,
                                         row_gate);
  cast_tokens<<<TOK * DIM / 8 / 256, 256, 0, stream>>>(tokens, X16);
  dim3 tg(16, 16, 8);
  transpose_cast<<<tg, 256, 0, stream>>>(w1, w1T);
  transpose_cast<<<tg, 256, 0, stream>>>(w2, w2T);
  // pass-0 merged: all 16 segments, 272 m-tiles x 8 n-tiles = 2176 blocks
  dgemm<0, 0><<<2176, 512, 0, stream>>>(X16, w1T, row_token, row_gate, ctrl, 0,
                                        NSEG, 272, H, out);
  // pass-1: k0 stores, k1 RMW (136 m-tiles x 8 n-tiles = 1088 blocks each)
  dgemm<1, 0><<<1088, 512, 0, stream>>>(H, w2T, row_token, row_gate, ctrl, 0,
                                        8, 136, H, out);
  dgemm<1, 1><<<1088, 512, 0, stream>>>(H, w2T, row_token, row_gate, ctrl, 8,
                                        NSEG, 136, H, out);
}

// Round 21
// 608.400 us; speedup vs baseline: 2.8944x; 2.8944x over previous
//
#include <hip/hip_runtime.h>
#include <hip/hip_bf16.h>
#include <math.h>
#include <stdint.h>

#define TOK 32768
#define DIM 1024
#define NE 8
#define NSEG 16                      /* (k, expert) segments */
#define BMCAP (2 * TOK + NSEG * 256) /* 69632 row slots (segments padded to 256) */

#define C_CNT(s) ((s) * 16)
#define C_CUR(s) (256 + (s) * 16)
#define C_SEG(s) (512 + (s))

typedef __attribute__((ext_vector_type(8))) short bf16x8;
typedef __attribute__((ext_vector_type(4))) float f32x4;
typedef unsigned short ushort_t;

__device__ __forceinline__ unsigned short f2b(float x) {
  union { float f; unsigned u; } v; v.f = x;
  unsigned r = v.u + 0x7fffu + ((v.u >> 16) & 1u);
  return (unsigned short)(r >> 16);
}

// fast gelu: logistic form of tanh-approx; |err vs erf-gelu| <= ~3e-4
__device__ __forceinline__ float gelu_fast(float x) {
  const float y2 = -1.5957691216057308f * x * fmaf(0.044715f, x * x, 1.0f);
  return x * __builtin_amdgcn_rcpf(1.0f + __expf(y2));
}

__device__ __forceinline__ void async16(void* lds, const void* g) {
  auto* lp = (__attribute__((address_space(3))) uint32_t*)lds;
  auto* gp = (__attribute__((address_space(1))) uint32_t*)(const_cast<void*>(g));
  __builtin_amdgcn_global_load_lds(gp, lp, 16, 0, 0);
}

// ---- router v3 (no atomics): FROZEN sequential fmaf chain ------------------
__global__ __launch_bounds__(256) void router_seq3(
    const float* __restrict__ tokens, const float* __restrict__ rw,
    int* __restrict__ topi, float* __restrict__ topv) {
  __shared__ float xs[2][32][132];
  __shared__ float wsh[2][8][132];
  __shared__ float sc[256];
  const int tid = threadIdx.x;
  const int e = tid & 7;
  const int tr = tid >> 3;
  const int t0 = blockIdx.x * 32;

  float4 lx0, lx1, lx2, lx3, lw;
  auto issue = [&](int c) {
    const int col = (tid & 31) * 4;
    lx0 = *(const float4*)&tokens[(size_t)(t0 + ((tid + 0) >> 5)) * DIM + c * 128 + col];
    lx1 = *(const float4*)&tokens[(size_t)(t0 + ((tid + 256) >> 5)) * DIM + c * 128 + col];
    lx2 = *(const float4*)&tokens[(size_t)(t0 + ((tid + 512) >> 5)) * DIM + c * 128 + col];
    lx3 = *(const float4*)&tokens[(size_t)(t0 + ((tid + 768) >> 5)) * DIM + c * 128 + col];
    lw  = *(const float4*)&rw[(size_t)(tid >> 5) * DIM + c * 128 + col];
  };
  auto commit = [&](int b) {
    const int col = (tid & 31) * 4;
    *(float4*)&xs[b][(tid + 0) >> 5][col] = lx0;
    *(float4*)&xs[b][(tid + 256) >> 5][col] = lx1;
    *(float4*)&xs[b][(tid + 512) >> 5][col] = lx2;
    *(float4*)&xs[b][(tid + 768) >> 5][col] = lx3;
    *(float4*)&wsh[b][tid >> 5][col] = lw;
  };

  issue(0);
  commit(0);
  __syncthreads();
  float s = 0.f;
  for (int c = 0; c < 8; c++) {
    const int b = c & 1;
    if (c + 1 < 8) issue(c + 1);
#pragma unroll
    for (int k4 = 0; k4 < 32; k4++) {
      const float4 xv = *(const float4*)&xs[b][tr][k4 * 4];
      const float4 wv = *(const float4*)&wsh[b][e][k4 * 4];
      s = fmaf(xv.x, wv.x, s);
      s = fmaf(xv.y, wv.y, s);
      s = fmaf(xv.z, wv.z, s);
      s = fmaf(xv.w, wv.w, s);
    }
    if (c + 1 < 8) commit(b ^ 1);
    __syncthreads();
  }
  sc[tid] = s;
  __syncthreads();
  if (e == 0) {
    float p[NE];
    float m = sc[tr * 8];
#pragma unroll
    for (int i = 1; i < NE; i++) m = fmaxf(m, sc[tr * 8 + i]);
    float sum = 0.f;
#pragma unroll
    for (int i = 0; i < NE; i++) {
      p[i] = expf(sc[tr * 8 + i] - m);
      sum += p[i];
    }
#pragma unroll
    for (int i = 0; i < NE; i++) p[i] = p[i] / sum;
    const int t = t0 + tr;
    int e0 = 0;
#pragma unroll
    for (int i = 1; i < NE; i++) if (p[i] > p[e0]) e0 = i;
    int e1 = (e0 == 0) ? 1 : 0;
#pragma unroll
    for (int i = 0; i < NE; i++) if (i != e0 && p[i] > p[e1]) e1 = i;
    topi[t * 2] = e0;     topv[t * 2] = p[e0];
    topi[t * 2 + 1] = e1; topv[t * 2 + 1] = p[e1];
  }
}

// ---- per-(k,expert) counts -------------------------------------------------
__global__ __launch_bounds__(256) void hist_kernel(const int* __restrict__ topi,
                                                   int* __restrict__ ctrl) {
  __shared__ int h[NSEG];
  const int tid = threadIdx.x;
  if (tid < NSEG) h[tid] = 0;
  __syncthreads();
  const int t = blockIdx.x * 256 + tid;
  atomicAdd(&h[topi[t * 2]], 1);
  atomicAdd(&h[8 + topi[t * 2 + 1]], 1);
  __syncthreads();
  if (tid < NSEG) atomicAdd(&ctrl[C_CNT(tid)], h[tid]);
}

__global__ void prefix_kernel(int* ctrl) {
  if (threadIdx.x == 0 && blockIdx.x == 0) {
    int s = 0;
    for (int g = 0; g < NSEG; g++) {
      ctrl[C_SEG(g)] = s;
      ctrl[C_CUR(g)] = s;
      s += (ctrl[C_CNT(g)] + 255) & ~255; /* pad segments to 256 (BM) */
    }
    ctrl[C_SEG(NSEG)] = s;
  }
}

__global__ __launch_bounds__(256) void init_rows(
    int* __restrict__ row_token, float* __restrict__ row_gate) {
  const int i = blockIdx.x * 256 + threadIdx.x;
  if (i < BMCAP) { row_token[i] = TOK; row_gate[i] = 0.f; }
}

__global__ __launch_bounds__(256) void assign2(
    const int* __restrict__ topi, const float* __restrict__ topv,
    int* __restrict__ ctrl, int* __restrict__ row_token,
    float* __restrict__ row_gate) {
  __shared__ int h[NSEG];
  __shared__ int base[NSEG];
  const int tid = threadIdx.x;
  const int t = blockIdx.x * 256 + tid;
  if (tid < NSEG) h[tid] = 0;
  __syncthreads();
  const int s0 = topi[t * 2], s1 = 8 + topi[t * 2 + 1];
  const int o0 = atomicAdd(&h[s0], 1);
  const int o1 = atomicAdd(&h[s1], 1);
  __syncthreads();
  if (tid < NSEG) base[tid] = atomicAdd(&ctrl[C_CUR(tid)], h[tid]);
  __syncthreads();
  const int p0 = base[s0] + o0, p1 = base[s1] + o1;
  row_token[p0] = t; row_gate[p0] = topv[t * 2];
  row_token[p1] = t; row_gate[p1] = topv[t * 2 + 1];
}

__global__ __launch_bounds__(256) void cast_tokens(
    const float* __restrict__ t, ushort_t* __restrict__ x16) {
  const size_t i = ((size_t)blockIdx.x * 256 + threadIdx.x) * 8;
  const float4 a = *(const float4*)(t + i);
  const float4 b = *(const float4*)(t + i + 4);
  bf16x8 h;
  h[0] = (short)f2b(a.x); h[1] = (short)f2b(a.y);
  h[2] = (short)f2b(a.z); h[3] = (short)f2b(a.w);
  h[4] = (short)f2b(b.x); h[5] = (short)f2b(b.y);
  h[6] = (short)f2b(b.z); h[7] = (short)f2b(b.w);
  *(bf16x8*)(x16 + i) = h;
}

__global__ __launch_bounds__(256) void transpose_cast(
    const float* __restrict__ w, ushort_t* __restrict__ wT) {
  __shared__ float tile[64][65];
  const int e = blockIdx.z;
  const int n0 = blockIdx.x * 64, k0 = blockIdx.y * 64;
  const int tx = threadIdx.x & 63, ty = threadIdx.x >> 6;
  const float* src = w + ((size_t)e << 20);
  ushort_t* dst = wT + ((size_t)e << 20);
#pragma unroll
  for (int r = ty; r < 64; r += 4)
    tile[r][tx] = src[(size_t)(k0 + r) * DIM + n0 + tx];
  __syncthreads();
#pragma unroll
  for (int r = ty; r < 64; r += 4)
    dst[(size_t)(n0 + r) * DIM + k0 + tx] = f2b(tile[tx][r]);
}

// --- grouped GEMM: 256x128 tile, BK=32, 8 waves, dbuf, 2 blocks/CU ----------
// launch_bounds(512,4): r19-VERIFIED (VGPR 64, no spills). (512,6) spilled
// the accumulator to scratch (r20: VGPR 40, 3.4 TB/s spill traffic, 3.2x slow)
// — do not raise the min-waves bound on this shape.
// Swizzle: granule ^= (row&3)^((row>>2)&3), both-sides (rule #21).
// Epilogue: 4 cross-wave rounds through 32KB scratch, coalesced wide stores.
template <int PASS, int ADD>
__global__ __launch_bounds__(512, 4) void dgemm(
    const ushort_t* __restrict__ Asrc, const ushort_t* __restrict__ Wt,
    const int* __restrict__ row_token, const float* __restrict__ row_gate,
    const int* __restrict__ ctrl, int s_lo, int s_hi, int chunk,
    ushort_t* __restrict__ Hout, float* __restrict__ out) {
  const int l = (blockIdx.x & 7) * chunk + (blockIdx.x >> 3);
  const int mt = l >> 3, nt = l & 7; // n-fastest: 8 blocks share an A-panel
  const int rbase0 = ctrl[C_SEG(s_lo)];
  const int rend = ctrl[C_SEG(s_hi)];
  const int m0 = rbase0 + mt * 256;
  if (m0 >= rend) return;
  const int n0 = nt * 128;
  int sg = s_lo;
  for (int i = s_lo + 1; i < s_hi; i++)
    if (m0 >= ctrl[C_SEG(i)]) sg = i;
  const int e = sg & 7;
  const ushort_t* B = Wt + ((size_t)e << 20);

  __shared__ __align__(16) char smem[49152];
  ushort_t (*As)[8192] = (ushort_t(*)[8192])smem;           // 2 x 16 KB
  ushort_t (*Bs)[4096] = (ushort_t(*)[4096])(smem + 32768); // 2 x 8 KB
  float* scratch = (float*)smem; // epilogue: 64x128 f32 = 32 KB

  const int tid = threadIdx.x;
  const int lane = tid & 63;
  const int wave = tid >> 6;
  const int wm = wave >> 1, wn = wave & 1; // per-wave 64x64 output
  const int lr = lane & 15;
  // read-side physical granule XOR (element offset, <<3 = *8 elems)
  const int kx = (((lane >> 4) ^ (lr & 3) ^ ((lr >> 2) & 3)) << 3);

  // staging: A rows w*32+(l>>2) (+16 for j=1), B rows w*16+(l>>2);
  // source col granule = (l&3)^((l>>2)&3)^((l>>4)&3)  (both-sides involution)
  const int ko = (((lane & 3) ^ ((lane >> 2) & 3) ^ ((lane >> 4) & 3)) << 3);
  const int ar0 = wave * 32 + (lane >> 2);
  const int brr = wave * 16 + (lane >> 2);
  const ushort_t *asrc0, *asrc1, *bsrc;
  if (PASS == 0) {
    int tk0 = row_token[m0 + ar0];
    int tk1 = row_token[m0 + ar0 + 16];
    if (tk0 >= TOK) tk0 = 0;
    if (tk1 >= TOK) tk1 = 0;
    asrc0 = Asrc + (size_t)tk0 * DIM + ko;
    asrc1 = Asrc + (size_t)tk1 * DIM + ko;
  } else {
    asrc0 = Asrc + (size_t)(m0 + ar0) * DIM + ko;
    asrc1 = Asrc + (size_t)(m0 + ar0 + 16) * DIM + ko;
  }
  bsrc = B + (size_t)(n0 + brr) * DIM + ko;

  f32x4 acc[4][4] = {};

  auto stage = [&](int b, int k0) {
    async16(&As[b][wave * 1024], asrc0 + k0);
    async16(&As[b][wave * 1024 + 512], asrc1 + k0);
    async16(&Bs[b][wave * 512], bsrc + k0);
  };
  auto compute = [&](int b) {
    bf16x8 a[4], bb[4];
#pragma unroll
    for (int mi = 0; mi < 4; mi++)
      a[mi] = *(const bf16x8*)&As[b][(wm * 64 + mi * 16 + lr) * 32 + kx];
#pragma unroll
    for (int ni = 0; ni < 4; ni++)
      bb[ni] = *(const bf16x8*)&Bs[b][(wn * 64 + ni * 16 + lr) * 32 + kx];
#pragma unroll
    for (int mi = 0; mi < 4; mi++)
#pragma unroll
      for (int ni = 0; ni < 4; ni++)
        acc[mi][ni] = __builtin_amdgcn_mfma_f32_16x16x32_bf16(
            a[mi], bb[ni], acc[mi][ni], 0, 0, 0);
  };

  stage(0, 0);
  __syncthreads();
  int cur = 0;
#pragma unroll 1
  for (int t = 0; t < 31; t++) {
    stage(cur ^ 1, (t + 1) * 32);
    compute(cur);
    __syncthreads();
    cur ^= 1;
  }
  compute(cur);
  __syncthreads(); // K-loop done; smem becomes scratch

  // ---- epilogue: 4 rounds (one 64-row m-block each) -----------------------
  const int grow = (lane >> 4) << 2;
  const int erow = tid >> 3;       // 0..63
  const int ec0 = (tid & 7) * 16;  // col base, 16 cols/thread
#pragma unroll 1
  for (int rnd = 0; rnd < 4; rnd++) {
    if (wm == rnd) {
#pragma unroll
      for (int mi = 0; mi < 4; mi++) {
#pragma unroll
        for (int ni = 0; ni < 4; ni++) {
#pragma unroll
          for (int r = 0; r < 4; r++) {
            const int lrow = mi * 16 + grow + r;
            const int lcol = (wn * 64 + ni * 16 + lr) ^ ((lrow & 3) << 2);
            scratch[lrow * 128 + lcol] = acc[mi][ni][r];
          }
        }
      }
    }
    __syncthreads();
    {
      const int q = (erow & 3) << 2;
      f32x4 v[4];
#pragma unroll
      for (int k = 0; k < 4; k++)
        v[k] = *(const f32x4*)&scratch[erow * 128 + ((ec0 + 4 * k) ^ q)];
      const int rr = m0 + rnd * 64 + erow;
      if (PASS == 0) {
        bf16x8 h0, h1;
#pragma unroll
        for (int k = 0; k < 2; k++)
#pragma unroll
          for (int j = 0; j < 4; j++)
            h0[k * 4 + j] = (short)f2b(gelu_fast(v[k][j]));
#pragma unroll
        for (int k = 0; k < 2; k++)
#pragma unroll
          for (int j = 0; j < 4; j++)
            h1[k * 4 + j] = (short)f2b(gelu_fast(v[2 + k][j]));
        *(bf16x8*)&Hout[(size_t)rr * DIM + n0 + ec0] = h0;
        *(bf16x8*)&Hout[(size_t)rr * DIM + n0 + ec0 + 8] = h1;
      } else {
        const int tok = row_token[rr];
        if (tok < TOK) {
          const float g = row_gate[rr];
          float* op = out + (size_t)tok * DIM + n0 + ec0;
#pragma unroll
          for (int k = 0; k < 4; k++) {
            f32x4 res;
            if (ADD) {
              const f32x4 old = *(const f32x4*)(op + 4 * k);
#pragma unroll
              for (int j = 0; j < 4; j++) res[j] = old[j] + g * v[k][j];
            } else {
#pragma unroll
              for (int j = 0; j < 4; j++) res[j] = g * v[k][j];
            }
            *(f32x4*)(op + 4 * k) = res;
          }
        }
      }
    }
    __syncthreads();
  }
}

extern "C" void kernel_launch(void* const* d_in, const int* in_sizes, int n_in,
                              void* d_out, int out_size, void* d_ws,
                              size_t ws_size, hipStream_t stream) {
  (void)in_sizes; (void)n_in; (void)ws_size; (void)out_size;
  const float* tokens = (const float*)d_in[0];
  const float* rw = (const float*)d_in[1];
  const float* w1 = (const float*)d_in[2];
  const float* w2 = (const float*)d_in[3];
  float* out = (float*)d_out;

  char* ws = (char*)d_ws;
  size_t off = 0;
  auto alloc = [&](size_t b) {
    size_t o = off;
    off += (b + 255) & ~(size_t)255;
    return o;
  };
  int* ctrl = (int*)(ws + alloc(4096));
  int* topi = (int*)(ws + alloc((size_t)TOK * 2 * 4));
  float* topv = (float*)(ws + alloc((size_t)TOK * 2 * 4));
  int* row_token = (int*)(ws + alloc((size_t)BMCAP * 4));
  float* row_gate = (float*)(ws + alloc((size_t)BMCAP * 4));
  ushort_t* X16 = (ushort_t*)(ws + alloc((size_t)TOK * DIM * 2));
  ushort_t* w1T = (ushort_t*)(ws + alloc((size_t)NE * DIM * DIM * 2));
  ushort_t* w2T = (ushort_t*)(ws + alloc((size_t)NE * DIM * DIM * 2));
  ushort_t* H = (ushort_t*)(ws + alloc((size_t)BMCAP * DIM * 2)); // unified

  hipMemsetAsync(ctrl, 0, 4096, stream);
  router_seq3<<<TOK / 32, 256, 0, stream>>>(tokens, rw, topi, topv);
  hist_kernel<<<TOK / 256, 256, 0, stream>>>(topi, ctrl);
  prefix_kernel<<<1, 64, 0, stream>>>(ctrl);
  init_rows<<<BMCAP / 256, 256, 0, stream>>>(row_token, row_gate);
  assign2<<<TOK / 256, 256, 0, stream>>>(topi, topv, ctrl, row_token,
                                         row_gate);
  cast_tokens<<<TOK * DIM / 8 / 256, 256, 0, stream>>>(tokens, X16);
  dim3 tg(16, 16, 8);
  transpose_cast<<<tg, 256, 0, stream>>>(w1, w1T);
  transpose_cast<<<tg, 256, 0, stream>>>(w2, w2T);
  // pass-0 merged: all 16 segments, 272 m-tiles x 8 n-tiles = 2176 blocks
  dgemm<0, 0><<<2176, 512, 0, stream>>>(X16, w1T, row_token, row_gate, ctrl, 0,
                                        NSEG, 272, H, out);
  // pass-1: k0 stores, k1 RMW (136 m-tiles x 8 n-tiles = 1088 blocks each)
  dgemm<1, 0><<<1088, 512, 0, stream>>>(H, w2T, row_token, row_gate, ctrl, 0,
                                        8, 136, H, out);
  dgemm<1, 1><<<1088, 512, 0, stream>>>(H, w2T, row_token, row_gate, ctrl, 8,
                                        NSEG, 136, H, out);
}

// Round 22
// 539.417 us; speedup vs baseline: 3.2645x; 1.1279x over previous
//
#include <hip/hip_runtime.h>
#include <hip/hip_bf16.h>
#include <math.h>
#include <stdint.h>

#define TOK 32768
#define DIM 1024
#define NE 8
#define NSEG 16                      /* (k, expert) segments */
#define BMCAP (2 * TOK + NSEG * 256) /* 69632 row slots (segments padded to 256) */

#define C_CNT(s) ((s) * 16)
#define C_CUR(s) (256 + (s) * 16)
#define C_SEG(s) (512 + (s))

typedef __attribute__((ext_vector_type(8))) short bf16x8;
typedef __attribute__((ext_vector_type(4))) float f32x4;
typedef unsigned short ushort_t;

__device__ __forceinline__ unsigned short f2b(float x) {
  union { float f; unsigned u; } v; v.f = x;
  unsigned r = v.u + 0x7fffu + ((v.u >> 16) & 1u);
  return (unsigned short)(r >> 16);
}

__device__ __forceinline__ float b2f(unsigned short u) {
  union { unsigned u; float f; } v;
  v.u = ((unsigned)u) << 16;
  return v.f;
}

// fast gelu: logistic form of tanh-approx; |err vs erf-gelu| <= ~3e-4
__device__ __forceinline__ float gelu_fast(float x) {
  const float y2 = -1.5957691216057308f * x * fmaf(0.044715f, x * x, 1.0f);
  return x * __builtin_amdgcn_rcpf(1.0f + __expf(y2));
}

__device__ __forceinline__ void async16(void* lds, const void* g) {
  auto* lp = (__attribute__((address_space(3))) uint32_t*)lds;
  auto* gp = (__attribute__((address_space(1))) uint32_t*)(const_cast<void*>(g));
  __builtin_amdgcn_global_load_lds(gp, lp, 16, 0, 0);
}

// ---- router v3 (no atomics): FROZEN sequential fmaf chain ------------------
__global__ __launch_bounds__(256) void router_seq3(
    const float* __restrict__ tokens, const float* __restrict__ rw,
    int* __restrict__ topi, float* __restrict__ topv) {
  __shared__ float xs[2][32][132];
  __shared__ float wsh[2][8][132];
  __shared__ float sc[256];
  const int tid = threadIdx.x;
  const int e = tid & 7;
  const int tr = tid >> 3;
  const int t0 = blockIdx.x * 32;

  float4 lx0, lx1, lx2, lx3, lw;
  auto issue = [&](int c) {
    const int col = (tid & 31) * 4;
    lx0 = *(const float4*)&tokens[(size_t)(t0 + ((tid + 0) >> 5)) * DIM + c * 128 + col];
    lx1 = *(const float4*)&tokens[(size_t)(t0 + ((tid + 256) >> 5)) * DIM + c * 128 + col];
    lx2 = *(const float4*)&tokens[(size_t)(t0 + ((tid + 512) >> 5)) * DIM + c * 128 + col];
    lx3 = *(const float4*)&tokens[(size_t)(t0 + ((tid + 768) >> 5)) * DIM + c * 128 + col];
    lw  = *(const float4*)&rw[(size_t)(tid >> 5) * DIM + c * 128 + col];
  };
  auto commit = [&](int b) {
    const int col = (tid & 31) * 4;
    *(float4*)&xs[b][(tid + 0) >> 5][col] = lx0;
    *(float4*)&xs[b][(tid + 256) >> 5][col] = lx1;
    *(float4*)&xs[b][(tid + 512) >> 5][col] = lx2;
    *(float4*)&xs[b][(tid + 768) >> 5][col] = lx3;
    *(float4*)&wsh[b][tid >> 5][col] = lw;
  };

  issue(0);
  commit(0);
  __syncthreads();
  float s = 0.f;
  for (int c = 0; c < 8; c++) {
    const int b = c & 1;
    if (c + 1 < 8) issue(c + 1);
#pragma unroll
    for (int k4 = 0; k4 < 32; k4++) {
      const float4 xv = *(const float4*)&xs[b][tr][k4 * 4];
      const float4 wv = *(const float4*)&wsh[b][e][k4 * 4];
      s = fmaf(xv.x, wv.x, s);
      s = fmaf(xv.y, wv.y, s);
      s = fmaf(xv.z, wv.z, s);
      s = fmaf(xv.w, wv.w, s);
    }
    if (c + 1 < 8) commit(b ^ 1);
    __syncthreads();
  }
  sc[tid] = s;
  __syncthreads();
  if (e == 0) {
    float p[NE];
    float m = sc[tr * 8];
#pragma unroll
    for (int i = 1; i < NE; i++) m = fmaxf(m, sc[tr * 8 + i]);
    float sum = 0.f;
#pragma unroll
    for (int i = 0; i < NE; i++) {
      p[i] = expf(sc[tr * 8 + i] - m);
      sum += p[i];
    }
#pragma unroll
    for (int i = 0; i < NE; i++) p[i] = p[i] / sum;
    const int t = t0 + tr;
    int e0 = 0;
#pragma unroll
    for (int i = 1; i < NE; i++) if (p[i] > p[e0]) e0 = i;
    int e1 = (e0 == 0) ? 1 : 0;
#pragma unroll
    for (int i = 0; i < NE; i++) if (i != e0 && p[i] > p[e1]) e1 = i;
    topi[t * 2] = e0;     topv[t * 2] = p[e0];
    topi[t * 2 + 1] = e1; topv[t * 2 + 1] = p[e1];
  }
}

// ---- per-(k,expert) counts -------------------------------------------------
__global__ __launch_bounds__(256) void hist_kernel(const int* __restrict__ topi,
                                                   int* __restrict__ ctrl) {
  __shared__ int h[NSEG];
  const int tid = threadIdx.x;
  if (tid < NSEG) h[tid] = 0;
  __syncthreads();
  const int t = blockIdx.x * 256 + tid;
  atomicAdd(&h[topi[t * 2]], 1);
  atomicAdd(&h[8 + topi[t * 2 + 1]], 1);
  __syncthreads();
  if (tid < NSEG) atomicAdd(&ctrl[C_CNT(tid)], h[tid]);
}

__global__ void prefix_kernel(int* ctrl) {
  if (threadIdx.x == 0 && blockIdx.x == 0) {
    int s = 0;
    for (int g = 0; g < NSEG; g++) {
      ctrl[C_SEG(g)] = s;
      ctrl[C_CUR(g)] = s;
      s += (ctrl[C_CNT(g)] + 255) & ~255; /* pad segments to 256 (BM) */
    }
    ctrl[C_SEG(NSEG)] = s;
  }
}

__global__ __launch_bounds__(256) void init_rows(int* __restrict__ row_token) {
  const int i = blockIdx.x * 256 + threadIdx.x;
  if (i < BMCAP) row_token[i] = TOK;
}

// ---- assign: slot scatter + inverse map (token -> slot) --------------------
__global__ __launch_bounds__(256) void assign2(
    const int* __restrict__ topi, int* __restrict__ ctrl,
    int* __restrict__ row_token, int* __restrict__ inv) {
  __shared__ int h[NSEG];
  __shared__ int base[NSEG];
  const int tid = threadIdx.x;
  const int t = blockIdx.x * 256 + tid;
  if (tid < NSEG) h[tid] = 0;
  __syncthreads();
  const int s0 = topi[t * 2], s1 = 8 + topi[t * 2 + 1];
  const int o0 = atomicAdd(&h[s0], 1);
  const int o1 = atomicAdd(&h[s1], 1);
  __syncthreads();
  if (tid < NSEG) base[tid] = atomicAdd(&ctrl[C_CUR(tid)], h[tid]);
  __syncthreads();
  const int p0 = base[s0] + o0, p1 = base[s1] + o1;
  row_token[p0] = t; inv[t * 2] = p0;
  row_token[p1] = t; inv[t * 2 + 1] = p1;
}

__global__ __launch_bounds__(256) void cast_tokens(
    const float* __restrict__ t, ushort_t* __restrict__ x16) {
  const size_t i = ((size_t)blockIdx.x * 256 + threadIdx.x) * 8;
  const float4 a = *(const float4*)(t + i);
  const float4 b = *(const float4*)(t + i + 4);
  bf16x8 h;
  h[0] = (short)f2b(a.x); h[1] = (short)f2b(a.y);
  h[2] = (short)f2b(a.z); h[3] = (short)f2b(a.w);
  h[4] = (short)f2b(b.x); h[5] = (short)f2b(b.y);
  h[6] = (short)f2b(b.z); h[7] = (short)f2b(b.w);
  *(bf16x8*)(x16 + i) = h;
}

__global__ __launch_bounds__(256) void transpose_cast(
    const float* __restrict__ w, ushort_t* __restrict__ wT) {
  __shared__ float tile[64][65];
  const int e = blockIdx.z;
  const int n0 = blockIdx.x * 64, k0 = blockIdx.y * 64;
  const int tx = threadIdx.x & 63, ty = threadIdx.x >> 6;
  const float* src = w + ((size_t)e << 20);
  ushort_t* dst = wT + ((size_t)e << 20);
#pragma unroll
  for (int r = ty; r < 64; r += 4)
    tile[r][tx] = src[(size_t)(k0 + r) * DIM + n0 + tx];
  __syncthreads();
#pragma unroll
  for (int r = ty; r < 64; r += 4)
    dst[(size_t)(n0 + r) * DIM + k0 + tx] = f2b(tile[tx][r]);
}

// ---- combine: out[t] = g0*gY[slot0] + g1*gY[slot1]  (coalesced, f32) -------
__global__ __launch_bounds__(256) void combine(
    const ushort_t* __restrict__ gY, const int* __restrict__ inv,
    const float* __restrict__ topv, float* __restrict__ out) {
  const size_t i = (size_t)blockIdx.x * 256 + threadIdx.x;
  const int t = (int)(i >> 7);
  const int c = (int)(i & 127) << 3;
  const int s0 = inv[t * 2], s1 = inv[t * 2 + 1];
  const float g0 = topv[t * 2], g1 = topv[t * 2 + 1];
  const bf16x8 y0 = *(const bf16x8*)&gY[(size_t)s0 * DIM + c];
  const bf16x8 y1 = *(const bf16x8*)&gY[(size_t)s1 * DIM + c];
  f32x4 o0, o1;
#pragma unroll
  for (int j = 0; j < 4; j++)
    o0[j] = g0 * b2f((unsigned short)y0[j]) + g1 * b2f((unsigned short)y1[j]);
#pragma unroll
  for (int j = 0; j < 4; j++)
    o1[j] = g0 * b2f((unsigned short)y0[4 + j]) +
            g1 * b2f((unsigned short)y1[4 + j]);
  float* op = out + (size_t)t * DIM + c;
  *(f32x4*)op = o0;
  *(f32x4*)(op + 4) = o1;
}

// --- grouped GEMM: 256x128 tile, BK=32, 8 waves, dbuf, 2 blocks/CU ----------
// launch_bounds(512,4): r19/r21-VERIFIED (VGPR ~64, no spills). (512,6)
// spilled the accumulator (r20, 3.2x slow) — do not raise.
// PASS 0: H[rr,:]  = gelu(X16[row_token[rr],:] @ w1T[e]^T)   (bf16 rows)
// PASS 1: gY[rr,:] =       H[rr,:]             @ w2T[e]^T    (bf16 rows)
// Both epilogues coalesced slot-row stores; gate applied later in combine.
template <int PASS>
__global__ __launch_bounds__(512, 4) void dgemm(
    const ushort_t* __restrict__ Asrc, const ushort_t* __restrict__ Wt,
    const int* __restrict__ row_token, const int* __restrict__ ctrl, int s_lo,
    int s_hi, int chunk, ushort_t* __restrict__ Hout) {
  const int l = (blockIdx.x & 7) * chunk + (blockIdx.x >> 3);
  const int mt = l >> 3, nt = l & 7; // n-fastest: 8 blocks share an A-panel
  const int rbase0 = ctrl[C_SEG(s_lo)];
  const int rend = ctrl[C_SEG(s_hi)];
  const int m0 = rbase0 + mt * 256;
  if (m0 >= rend) return;
  const int n0 = nt * 128;
  int sg = s_lo;
  for (int i = s_lo + 1; i < s_hi; i++)
    if (m0 >= ctrl[C_SEG(i)]) sg = i;
  const int e = sg & 7;
  const ushort_t* B = Wt + ((size_t)e << 20);

  __shared__ __align__(16) char smem[49152];
  ushort_t (*As)[8192] = (ushort_t(*)[8192])smem;           // 2 x 16 KB
  ushort_t (*Bs)[4096] = (ushort_t(*)[4096])(smem + 32768); // 2 x 8 KB
  float* scratch = (float*)smem; // epilogue: 64x128 f32 = 32 KB

  const int tid = threadIdx.x;
  const int lane = tid & 63;
  const int wave = tid >> 6;
  const int wm = wave >> 1, wn = wave & 1; // per-wave 64x64 output
  const int lr = lane & 15;
  const int kx = (((lane >> 4) ^ (lr & 3) ^ ((lr >> 2) & 3)) << 3);

  const int ko = (((lane & 3) ^ ((lane >> 2) & 3) ^ ((lane >> 4) & 3)) << 3);
  const int ar0 = wave * 32 + (lane >> 2);
  const int brr = wave * 16 + (lane >> 2);
  const ushort_t *asrc0, *asrc1, *bsrc;
  if (PASS == 0) {
    int tk0 = row_token[m0 + ar0];
    int tk1 = row_token[m0 + ar0 + 16];
    if (tk0 >= TOK) tk0 = 0;
    if (tk1 >= TOK) tk1 = 0;
    asrc0 = Asrc + (size_t)tk0 * DIM + ko;
    asrc1 = Asrc + (size_t)tk1 * DIM + ko;
  } else {
    asrc0 = Asrc + (size_t)(m0 + ar0) * DIM + ko;
    asrc1 = Asrc + (size_t)(m0 + ar0 + 16) * DIM + ko;
  }
  bsrc = B + (size_t)(n0 + brr) * DIM + ko;

  f32x4 acc[4][4] = {};

  auto stage = [&](int b, int k0) {
    async16(&As[b][wave * 1024], asrc0 + k0);
    async16(&As[b][wave * 1024 + 512], asrc1 + k0);
    async16(&Bs[b][wave * 512], bsrc + k0);
  };
  auto compute = [&](int b) {
    bf16x8 a[4], bb[4];
#pragma unroll
    for (int mi = 0; mi < 4; mi++)
      a[mi] = *(const bf16x8*)&As[b][(wm * 64 + mi * 16 + lr) * 32 + kx];
#pragma unroll
    for (int ni = 0; ni < 4; ni++)
      bb[ni] = *(const bf16x8*)&Bs[b][(wn * 64 + ni * 16 + lr) * 32 + kx];
#pragma unroll
    for (int mi = 0; mi < 4; mi++)
#pragma unroll
      for (int ni = 0; ni < 4; ni++)
        acc[mi][ni] = __builtin_amdgcn_mfma_f32_16x16x32_bf16(
            a[mi], bb[ni], acc[mi][ni], 0, 0, 0);
  };

  stage(0, 0);
  __syncthreads();
  int cur = 0;
#pragma unroll 1
  for (int t = 0; t < 31; t++) {
    stage(cur ^ 1, (t + 1) * 32);
    compute(cur);
    __syncthreads();
    cur ^= 1;
  }
  compute(cur);
  __syncthreads(); // K-loop done; smem becomes scratch

  // ---- epilogue: 4 rounds (one 64-row m-block each), coalesced stores -----
  const int grow = (lane >> 4) << 2;
  const int erow = tid >> 3;       // 0..63
  const int ec0 = (tid & 7) * 16;  // col base, 16 cols/thread
#pragma unroll 1
  for (int rnd = 0; rnd < 4; rnd++) {
    if (wm == rnd) {
#pragma unroll
      for (int mi = 0; mi < 4; mi++) {
#pragma unroll
        for (int ni = 0; ni < 4; ni++) {
#pragma unroll
          for (int r = 0; r < 4; r++) {
            const int lrow = mi * 16 + grow + r;
            const int lcol = (wn * 64 + ni * 16 + lr) ^ ((lrow & 3) << 2);
            scratch[lrow * 128 + lcol] = acc[mi][ni][r];
          }
        }
      }
    }
    __syncthreads();
    {
      const int q = (erow & 3) << 2;
      f32x4 v[4];
#pragma unroll
      for (int k = 0; k < 4; k++)
        v[k] = *(const f32x4*)&scratch[erow * 128 + ((ec0 + 4 * k) ^ q)];
      const int rr = m0 + rnd * 64 + erow;
      bf16x8 h0, h1;
      if (PASS == 0) {
#pragma unroll
        for (int k = 0; k < 2; k++)
#pragma unroll
          for (int j = 0; j < 4; j++)
            h0[k * 4 + j] = (short)f2b(gelu_fast(v[k][j]));
#pragma unroll
        for (int k = 0; k < 2; k++)
#pragma unroll
          for (int j = 0; j < 4; j++)
            h1[k * 4 + j] = (short)f2b(gelu_fast(v[2 + k][j]));
      } else {
#pragma unroll
        for (int k = 0; k < 2; k++)
#pragma unroll
          for (int j = 0; j < 4; j++) h0[k * 4 + j] = (short)f2b(v[k][j]);
#pragma unroll
        for (int k = 0; k < 2; k++)
#pragma unroll
          for (int j = 0; j < 4; j++) h1[k * 4 + j] = (short)f2b(v[2 + k][j]);
      }
      *(bf16x8*)&Hout[(size_t)rr * DIM + n0 + ec0] = h0;
      *(bf16x8*)&Hout[(size_t)rr * DIM + n0 + ec0 + 8] = h1;
    }
    __syncthreads();
  }
}

extern "C" void kernel_launch(void* const* d_in, const int* in_sizes, int n_in,
                              void* d_out, int out_size, void* d_ws,
                              size_t ws_size, hipStream_t stream) {
  (void)in_sizes; (void)n_in; (void)ws_size; (void)out_size;
  const float* tokens = (const float*)d_in[0];
  const float* rw = (const float*)d_in[1];
  const float* w1 = (const float*)d_in[2];
  const float* w2 = (const float*)d_in[3];
  float* out = (float*)d_out;

  char* ws = (char*)d_ws;
  size_t off = 0;
  auto alloc = [&](size_t b) {
    size_t o = off;
    off += (b + 255) & ~(size_t)255;
    return o;
  };
  int* ctrl = (int*)(ws + alloc(4096));
  int* topi = (int*)(ws + alloc((size_t)TOK * 2 * 4));
  float* topv = (float*)(ws + alloc((size_t)TOK * 2 * 4));
  int* inv = (int*)(ws + alloc((size_t)TOK * 2 * 4));
  int* row_token = (int*)(ws + alloc((size_t)BMCAP * 4));
  ushort_t* w2T = (ushort_t*)(ws + alloc((size_t)NE * DIM * DIM * 2));
  ushort_t* H = (ushort_t*)(ws + alloc((size_t)BMCAP * DIM * 2));
  // region: X16 + w1T (pass-0 only) overlaid by gY (pass-1 output)
  const size_t region = alloc((size_t)BMCAP * DIM * 2); // 142.6 MB
  ushort_t* X16 = (ushort_t*)(ws + region);                       // 67 MB
  ushort_t* w1T = (ushort_t*)(ws + region + (size_t)TOK * DIM * 2); // 16.8 MB
  ushort_t* gY = (ushort_t*)(ws + region); // aliases X16+w1T (dead by pass-1)

  hipMemsetAsync(ctrl, 0, 4096, stream);
  router_seq3<<<TOK / 32, 256, 0, stream>>>(tokens, rw, topi, topv);
  hist_kernel<<<TOK / 256, 256, 0, stream>>>(topi, ctrl);
  prefix_kernel<<<1, 64, 0, stream>>>(ctrl);
  init_rows<<<BMCAP / 256, 256, 0, stream>>>(row_token);
  assign2<<<TOK / 256, 256, 0, stream>>>(topi, ctrl, row_token, inv);
  cast_tokens<<<TOK * DIM / 8 / 256, 256, 0, stream>>>(tokens, X16);
  dim3 tg(16, 16, 8);
  transpose_cast<<<tg, 256, 0, stream>>>(w1, w1T);
  transpose_cast<<<tg, 256, 0, stream>>>(w2, w2T);
  // pass-0: all 16 segments -> H (272 m-tiles x 8 n-tiles = 2176 blocks)
  dgemm<0><<<2176, 512, 0, stream>>>(X16, w1T, row_token, ctrl, 0, NSEG, 272,
                                     H);
  // pass-1: all 16 segments -> gY (coalesced, no scatter/atomics/RMW)
  dgemm<1><<<2176, 512, 0, stream>>>(H, w2T, row_token, ctrl, 0, NSEG, 272,
                                     gY);
  // combine: out[t] = g0*gY[slot0] + g1*gY[slot1]
  combine<<<TOK * (DIM / 8) / 256, 256, 0, stream>>>(gY, inv, topv, out);
}

// Round 23
// 522.430 us; speedup vs baseline: 3.3707x; 1.0325x over previous
//
#include <hip/hip_runtime.h>
#include <hip/hip_bf16.h>
#include <math.h>
#include <stdint.h>

#define TOK 32768
#define DIM 1024
#define NE 8
#define NSEG 16                      /* (k, expert) segments */
#define BMCAP (2 * TOK + NSEG * 256) /* 69632 row slots (segments padded to 256) */

#define C_CNT(s) ((s) * 16)
#define C_CUR(s) (256 + (s) * 16)
#define C_SEG(s) (512 + (s))

typedef __attribute__((ext_vector_type(8))) short bf16x8;
typedef __attribute__((ext_vector_type(4))) float f32x4;
typedef __attribute__((ext_vector_type(4))) unsigned short u16x4;
typedef unsigned short ushort_t;

__device__ __forceinline__ unsigned short f2b(float x) {
  union { float f; unsigned u; } v; v.f = x;
  unsigned r = v.u + 0x7fffu + ((v.u >> 16) & 1u);
  return (unsigned short)(r >> 16);
}

__device__ __forceinline__ float b2f(unsigned short u) {
  union { unsigned u; float f; } v;
  v.u = ((unsigned)u) << 16;
  return v.f;
}

// fast gelu: logistic form of tanh-approx; |err vs erf-gelu| <= ~3e-4
__device__ __forceinline__ float gelu_fast(float x) {
  const float y2 = -1.5957691216057308f * x * fmaf(0.044715f, x * x, 1.0f);
  return x * __builtin_amdgcn_rcpf(1.0f + __expf(y2));
}

__device__ __forceinline__ void async16(void* lds, const void* g) {
  auto* lp = (__attribute__((address_space(3))) uint32_t*)lds;
  auto* gp = (__attribute__((address_space(1))) uint32_t*)(const_cast<void*>(g));
  __builtin_amdgcn_global_load_lds(gp, lp, 16, 0, 0);
}

// ---- router v4: FROZEN sequential fmaf chain + fused X16 cast --------------
__global__ __launch_bounds__(256) void router_seq3(
    const float* __restrict__ tokens, const float* __restrict__ rw,
    int* __restrict__ topi, float* __restrict__ topv,
    ushort_t* __restrict__ x16) {
  __shared__ float xs[2][32][132];
  __shared__ float wsh[2][8][132];
  __shared__ float sc[256];
  const int tid = threadIdx.x;
  const int e = tid & 7;
  const int tr = tid >> 3;
  const int t0 = blockIdx.x * 32;

  float4 lx0, lx1, lx2, lx3, lw;
  auto issue = [&](int c) {
    const int col = (tid & 31) * 4;
    lx0 = *(const float4*)&tokens[(size_t)(t0 + ((tid + 0) >> 5)) * DIM + c * 128 + col];
    lx1 = *(const float4*)&tokens[(size_t)(t0 + ((tid + 256) >> 5)) * DIM + c * 128 + col];
    lx2 = *(const float4*)&tokens[(size_t)(t0 + ((tid + 512) >> 5)) * DIM + c * 128 + col];
    lx3 = *(const float4*)&tokens[(size_t)(t0 + ((tid + 768) >> 5)) * DIM + c * 128 + col];
    lw  = *(const float4*)&rw[(size_t)(tid >> 5) * DIM + c * 128 + col];
  };
  auto commit = [&](int b) {
    const int col = (tid & 31) * 4;
    *(float4*)&xs[b][(tid + 0) >> 5][col] = lx0;
    *(float4*)&xs[b][(tid + 256) >> 5][col] = lx1;
    *(float4*)&xs[b][(tid + 512) >> 5][col] = lx2;
    *(float4*)&xs[b][(tid + 768) >> 5][col] = lx3;
    *(float4*)&wsh[b][tid >> 5][col] = lw;
  };
  auto commitX = [&](int c) { // fused tokens->bf16 (same RNE as cast_tokens)
    const int col = c * 128 + (tid & 31) * 4;
    u16x4 u;
    u[0] = f2b(lx0.x); u[1] = f2b(lx0.y); u[2] = f2b(lx0.z); u[3] = f2b(lx0.w);
    *(u16x4*)&x16[(size_t)(t0 + ((tid + 0) >> 5)) * DIM + col] = u;
    u[0] = f2b(lx1.x); u[1] = f2b(lx1.y); u[2] = f2b(lx1.z); u[3] = f2b(lx1.w);
    *(u16x4*)&x16[(size_t)(t0 + ((tid + 256) >> 5)) * DIM + col] = u;
    u[0] = f2b(lx2.x); u[1] = f2b(lx2.y); u[2] = f2b(lx2.z); u[3] = f2b(lx2.w);
    *(u16x4*)&x16[(size_t)(t0 + ((tid + 512) >> 5)) * DIM + col] = u;
    u[0] = f2b(lx3.x); u[1] = f2b(lx3.y); u[2] = f2b(lx3.z); u[3] = f2b(lx3.w);
    *(u16x4*)&x16[(size_t)(t0 + ((tid + 768) >> 5)) * DIM + col] = u;
  };

  issue(0);
  commit(0);
  commitX(0);
  __syncthreads();
  float s = 0.f;
  for (int c = 0; c < 8; c++) {
    const int b = c & 1;
    if (c + 1 < 8) issue(c + 1);
#pragma unroll
    for (int k4 = 0; k4 < 32; k4++) {
      const float4 xv = *(const float4*)&xs[b][tr][k4 * 4];
      const float4 wv = *(const float4*)&wsh[b][e][k4 * 4];
      s = fmaf(xv.x, wv.x, s);
      s = fmaf(xv.y, wv.y, s);
      s = fmaf(xv.z, wv.z, s);
      s = fmaf(xv.w, wv.w, s);
    }
    if (c + 1 < 8) {
      commit(b ^ 1);
      commitX(c + 1);
    }
    __syncthreads();
  }
  sc[tid] = s;
  __syncthreads();
  if (e == 0) {
    float p[NE];
    float m = sc[tr * 8];
#pragma unroll
    for (int i = 1; i < NE; i++) m = fmaxf(m, sc[tr * 8 + i]);
    float sum = 0.f;
#pragma unroll
    for (int i = 0; i < NE; i++) {
      p[i] = expf(sc[tr * 8 + i] - m);
      sum += p[i];
    }
#pragma unroll
    for (int i = 0; i < NE; i++) p[i] = p[i] / sum;
    const int t = t0 + tr;
    int e0 = 0;
#pragma unroll
    for (int i = 1; i < NE; i++) if (p[i] > p[e0]) e0 = i;
    int e1 = (e0 == 0) ? 1 : 0;
#pragma unroll
    for (int i = 0; i < NE; i++) if (i != e0 && p[i] > p[e1]) e1 = i;
    topi[t * 2] = e0;     topv[t * 2] = p[e0];
    topi[t * 2 + 1] = e1; topv[t * 2 + 1] = p[e1];
  }
}

// ---- per-(k,expert) counts -------------------------------------------------
__global__ __launch_bounds__(256) void hist_kernel(const int* __restrict__ topi,
                                                   int* __restrict__ ctrl) {
  __shared__ int h[NSEG];
  const int tid = threadIdx.x;
  if (tid < NSEG) h[tid] = 0;
  __syncthreads();
  const int t = blockIdx.x * 256 + tid;
  atomicAdd(&h[topi[t * 2]], 1);
  atomicAdd(&h[8 + topi[t * 2 + 1]], 1);
  __syncthreads();
  if (tid < NSEG) atomicAdd(&ctrl[C_CNT(tid)], h[tid]);
}

__global__ void prefix_kernel(int* ctrl) {
  if (threadIdx.x == 0 && blockIdx.x == 0) {
    int s = 0;
    for (int g = 0; g < NSEG; g++) {
      ctrl[C_SEG(g)] = s;
      ctrl[C_CUR(g)] = s;
      s += (ctrl[C_CNT(g)] + 255) & ~255; /* pad segments to 256 (BM) */
    }
    ctrl[C_SEG(NSEG)] = s;
  }
}

__global__ __launch_bounds__(256) void init_rows(int* __restrict__ row_token) {
  const int i = blockIdx.x * 256 + threadIdx.x;
  if (i < BMCAP) row_token[i] = TOK;
}

// ---- assign: slot scatter + inverse map (token -> slot) --------------------
__global__ __launch_bounds__(256) void assign2(
    const int* __restrict__ topi, int* __restrict__ ctrl,
    int* __restrict__ row_token, int* __restrict__ inv) {
  __shared__ int h[NSEG];
  __shared__ int base[NSEG];
  const int tid = threadIdx.x;
  const int t = blockIdx.x * 256 + tid;
  if (tid < NSEG) h[tid] = 0;
  __syncthreads();
  const int s0 = topi[t * 2], s1 = 8 + topi[t * 2 + 1];
  const int o0 = atomicAdd(&h[s0], 1);
  const int o1 = atomicAdd(&h[s1], 1);
  __syncthreads();
  if (tid < NSEG) base[tid] = atomicAdd(&ctrl[C_CUR(tid)], h[tid]);
  __syncthreads();
  const int p0 = base[s0] + o0, p1 = base[s1] + o1;
  row_token[p0] = t; inv[t * 2] = p0;
  row_token[p1] = t; inv[t * 2 + 1] = p1;
}

__global__ __launch_bounds__(256) void transpose_cast(
    const float* __restrict__ w, ushort_t* __restrict__ wT) {
  __shared__ float tile[64][65];
  const int e = blockIdx.z;
  const int n0 = blockIdx.x * 64, k0 = blockIdx.y * 64;
  const int tx = threadIdx.x & 63, ty = threadIdx.x >> 6;
  const float* src = w + ((size_t)e << 20);
  ushort_t* dst = wT + ((size_t)e << 20);
#pragma unroll
  for (int r = ty; r < 64; r += 4)
    tile[r][tx] = src[(size_t)(k0 + r) * DIM + n0 + tx];
  __syncthreads();
#pragma unroll
  for (int r = ty; r < 64; r += 4)
    dst[(size_t)(n0 + r) * DIM + k0 + tx] = f2b(tile[tx][r]);
}

// ---- combine: out[t] = g0*gY[slot0] + g1*gY[slot1]  (coalesced, f32) -------
__global__ __launch_bounds__(256) void combine(
    const ushort_t* __restrict__ gY, const int* __restrict__ inv,
    const float* __restrict__ topv, float* __restrict__ out) {
  const size_t i = (size_t)blockIdx.x * 256 + threadIdx.x;
  const int t = (int)(i >> 7);
  const int c = (int)(i & 127) << 3;
  const int s0 = inv[t * 2], s1 = inv[t * 2 + 1];
  const float g0 = topv[t * 2], g1 = topv[t * 2 + 1];
  const bf16x8 y0 = *(const bf16x8*)&gY[(size_t)s0 * DIM + c];
  const bf16x8 y1 = *(const bf16x8*)&gY[(size_t)s1 * DIM + c];
  f32x4 o0, o1;
#pragma unroll
  for (int j = 0; j < 4; j++)
    o0[j] = g0 * b2f((unsigned short)y0[j]) + g1 * b2f((unsigned short)y1[j]);
#pragma unroll
  for (int j = 0; j < 4; j++)
    o1[j] = g0 * b2f((unsigned short)y0[4 + j]) +
            g1 * b2f((unsigned short)y1[4 + j]);
  float* op = out + (size_t)t * DIM + c;
  *(f32x4*)op = o0;
  *(f32x4*)(op + 4) = o1;
}

// --- grouped GEMM: 256x128 tile, BK=32, 4 waves, per-wave 64x128 ------------
// LDS-read economy: 12 b128 per 32 MFMA (was 16) — LDS pipe was the binding
// resource (r22 audit: 960 LDS-cyc vs 620 MFMA-cyc per block-K-iter).
// launch_bounds(256,2): 256-VGPR cap (acc=128, no spill), 2 blocks/CU (96KB).
// Swizzle: granule ^= (row&3)^((row>>2)&3), both-sides (rule #21, r22-verified)
template <int PASS>
__global__ __launch_bounds__(256, 2) void dgemm(
    const ushort_t* __restrict__ Asrc, const ushort_t* __restrict__ Wt,
    const int* __restrict__ row_token, const int* __restrict__ ctrl, int s_lo,
    int s_hi, int chunk, ushort_t* __restrict__ Hout) {
  const int l = (blockIdx.x & 7) * chunk + (blockIdx.x >> 3);
  const int mt = l >> 3, nt = l & 7; // n-fastest: 8 blocks share an A-panel
  const int rbase0 = ctrl[C_SEG(s_lo)];
  const int rend = ctrl[C_SEG(s_hi)];
  const int m0 = rbase0 + mt * 256;
  if (m0 >= rend) return;
  const int n0 = nt * 128;
  int sg = s_lo;
  for (int i = s_lo + 1; i < s_hi; i++)
    if (m0 >= ctrl[C_SEG(i)]) sg = i;
  const int e = sg & 7;
  const ushort_t* B = Wt + ((size_t)e << 20);

  __shared__ __align__(16) char smem[49152];
  ushort_t (*As)[8192] = (ushort_t(*)[8192])smem;           // 2 x 16 KB (256x32)
  ushort_t (*Bs)[4096] = (ushort_t(*)[4096])(smem + 32768); // 2 x 8 KB (128x32)
  float* scratch = (float*)smem; // epilogue: 64x128 f32 = 32 KB

  const int tid = threadIdx.x;   // 0..255
  const int lane = tid & 63;
  const int wave = tid >> 6;     // 0..3 ; per-wave rows wave*64..+63, all 128 cols
  const int lr = lane & 15;
  const int kx = (((lane >> 4) ^ (lr & 3) ^ ((lr >> 2) & 3)) << 3);
  const int ko = (((lane & 3) ^ ((lane >> 2) & 3) ^ ((lane >> 4) & 3)) << 3);

  // staging: A chunks j=0..3 rows wave*64+j*16+(lane>>2); B j=0..1 rows
  // wave*32+j*16+(lane>>2). swz(row)=(row&3)^((row>>2)&3) matches ko (16-row
  // chunk bases are multiples of 16 -> contribute 0).
  const ushort_t* asrc[4];
  const ushort_t* bsrc[2];
#pragma unroll
  for (int j = 0; j < 4; j++) {
    const int rA = wave * 64 + j * 16 + (lane >> 2);
    if (PASS == 0) {
      int tk = row_token[m0 + rA];
      if (tk >= TOK) tk = 0;
      asrc[j] = Asrc + (size_t)tk * DIM + ko;
    } else {
      asrc[j] = Asrc + (size_t)(m0 + rA) * DIM + ko;
    }
  }
#pragma unroll
  for (int j = 0; j < 2; j++) {
    const int rB = wave * 32 + j * 16 + (lane >> 2);
    bsrc[j] = B + (size_t)(n0 + rB) * DIM + ko;
  }

  f32x4 acc[4][8] = {};

  auto stage = [&](int b, int k0) {
#pragma unroll
    for (int j = 0; j < 4; j++)
      async16(&As[b][wave * 2048 + j * 512], asrc[j] + k0);
#pragma unroll
    for (int j = 0; j < 2; j++)
      async16(&Bs[b][wave * 1024 + j * 512], bsrc[j] + k0);
  };
  auto compute = [&](int b) {
    bf16x8 a[4], bb[8];
#pragma unroll
    for (int mi = 0; mi < 4; mi++)
      a[mi] = *(const bf16x8*)&As[b][(wave * 64 + mi * 16 + lr) * 32 + kx];
#pragma unroll
    for (int ni = 0; ni < 8; ni++)
      bb[ni] = *(const bf16x8*)&Bs[b][(ni * 16 + lr) * 32 + kx];
#pragma unroll
    for (int mi = 0; mi < 4; mi++)
#pragma unroll
      for (int ni = 0; ni < 8; ni++)
        acc[mi][ni] = __builtin_amdgcn_mfma_f32_16x16x32_bf16(
            a[mi], bb[ni], acc[mi][ni], 0, 0, 0);
  };

  stage(0, 0);
  __syncthreads();
  int cur = 0;
#pragma unroll 1
  for (int t = 0; t < 31; t++) {
    stage(cur ^ 1, (t + 1) * 32);
    compute(cur);
    __syncthreads();
    cur ^= 1;
  }
  compute(cur);
  __syncthreads(); // K-loop done; smem becomes scratch

  // ---- epilogue: 4 rounds (wave rnd dumps its 64x128 window) --------------
  const int grow = (lane >> 4) << 2;
  const int erow = tid >> 2;       // 0..63
  const int ec0 = (tid & 3) * 32;  // 32 cols per thread
#pragma unroll 1
  for (int rnd = 0; rnd < 4; rnd++) {
    if (wave == rnd) {
#pragma unroll
      for (int mi = 0; mi < 4; mi++) {
#pragma unroll
        for (int ni = 0; ni < 8; ni++) {
#pragma unroll
          for (int r = 0; r < 4; r++) {
            const int lrow = mi * 16 + grow + r;
            const int lcol = (ni * 16 + lr) ^ ((lrow & 3) << 2);
            scratch[lrow * 128 + lcol] = acc[mi][ni][r];
          }
        }
      }
    }
    __syncthreads();
    {
      const int q = (erow & 3) << 2;
      f32x4 v[8];
#pragma unroll
      for (int k = 0; k < 8; k++)
        v[k] = *(const f32x4*)&scratch[erow * 128 + ((ec0 + 4 * k) ^ q)];
      const int rr = m0 + rnd * 64 + erow;
      ushort_t* dst = &Hout[(size_t)rr * DIM + n0 + ec0];
#pragma unroll
      for (int half = 0; half < 4; half++) {
        bf16x8 h;
        if (PASS == 0) {
#pragma unroll
          for (int j = 0; j < 4; j++)
            h[j] = (short)f2b(gelu_fast(v[half * 2][j]));
#pragma unroll
          for (int j = 0; j < 4; j++)
            h[4 + j] = (short)f2b(gelu_fast(v[half * 2 + 1][j]));
        } else {
#pragma unroll
          for (int j = 0; j < 4; j++) h[j] = (short)f2b(v[half * 2][j]);
#pragma unroll
          for (int j = 0; j < 4; j++) h[4 + j] = (short)f2b(v[half * 2 + 1][j]);
        }
        *(bf16x8*)(dst + half * 8) = h;
      }
    }
    __syncthreads();
  }
}

extern "C" void kernel_launch(void* const* d_in, const int* in_sizes, int n_in,
                              void* d_out, int out_size, void* d_ws,
                              size_t ws_size, hipStream_t stream) {
  (void)in_sizes; (void)n_in; (void)ws_size; (void)out_size;
  const float* tokens = (const float*)d_in[0];
  const float* rw = (const float*)d_in[1];
  const float* w1 = (const float*)d_in[2];
  const float* w2 = (const float*)d_in[3];
  float* out = (float*)d_out;

  char* ws = (char*)d_ws;
  size_t off = 0;
  auto alloc = [&](size_t b) {
    size_t o = off;
    off += (b + 255) & ~(size_t)255;
    return o;
  };
  int* ctrl = (int*)(ws + alloc(4096));
  int* topi = (int*)(ws + alloc((size_t)TOK * 2 * 4));
  float* topv = (float*)(ws + alloc((size_t)TOK * 2 * 4));
  int* inv = (int*)(ws + alloc((size_t)TOK * 2 * 4));
  int* row_token = (int*)(ws + alloc((size_t)BMCAP * 4));
  ushort_t* w2T = (ushort_t*)(ws + alloc((size_t)NE * DIM * DIM * 2));
  ushort_t* H = (ushort_t*)(ws + alloc((size_t)BMCAP * DIM * 2));
  // region: X16 + w1T (pass-0 only) overlaid by gY (pass-1 output)
  const size_t region = alloc((size_t)BMCAP * DIM * 2); // 142.6 MB
  ushort_t* X16 = (ushort_t*)(ws + region);                         // 67 MB
  ushort_t* w1T = (ushort_t*)(ws + region + (size_t)TOK * DIM * 2); // 16.8 MB
  ushort_t* gY = (ushort_t*)(ws + region); // aliases X16+w1T (dead by pass-1)

  hipMemsetAsync(ctrl, 0, 4096, stream);
  router_seq3<<<TOK / 32, 256, 0, stream>>>(tokens, rw, topi, topv, X16);
  hist_kernel<<<TOK / 256, 256, 0, stream>>>(topi, ctrl);
  prefix_kernel<<<1, 64, 0, stream>>>(ctrl);
  init_rows<<<BMCAP / 256, 256, 0, stream>>>(row_token);
  assign2<<<TOK / 256, 256, 0, stream>>>(topi, ctrl, row_token, inv);
  dim3 tg(16, 16, 8);
  transpose_cast<<<tg, 256, 0, stream>>>(w1, w1T);
  transpose_cast<<<tg, 256, 0, stream>>>(w2, w2T);
  // pass-0: all 16 segments -> H (272 m-tiles x 8 n-tiles = 2176 blocks)
  dgemm<0><<<2176, 256, 0, stream>>>(X16, w1T, row_token, ctrl, 0, NSEG, 272,
                                     H);
  // pass-1: all 16 segments -> gY (coalesced, no scatter/atomics/RMW)
  dgemm<1><<<2176, 256, 0, stream>>>(H, w2T, row_token, ctrl, 0, NSEG, 272,
                                     gY);
  // combine: out[t] = g0*gY[slot0] + g1*gY[slot1]
  combine<<<TOK * (DIM / 8) / 256, 256, 0, stream>>>(gY, inv, topv, out);
}

// Round 24
// 504.477 us; speedup vs baseline: 3.4906x; 1.0356x over previous
//
#include <hip/hip_runtime.h>
#include <hip/hip_bf16.h>
#include <math.h>
#include <stdint.h>

#define TOK 32768
#define DIM 1024
#define NE 8
#define NSEG 16                      /* (k, expert) segments */
#define BMCAP (2 * TOK + NSEG * 256) /* 69632 row slots (segments padded to 256) */

#define C_CNT(s) ((s) * 16)
#define C_CUR(s) (256 + (s) * 16)
#define C_SEG(s) (512 + (s))

typedef __attribute__((ext_vector_type(8))) short bf16x8;
typedef __attribute__((ext_vector_type(4))) float f32x4;
typedef __attribute__((ext_vector_type(4))) unsigned short u16x4;
typedef unsigned short ushort_t;

__device__ __forceinline__ unsigned short f2b(float x) {
  union { float f; unsigned u; } v; v.f = x;
  unsigned r = v.u + 0x7fffu + ((v.u >> 16) & 1u);
  return (unsigned short)(r >> 16);
}

__device__ __forceinline__ float b2f(unsigned short u) {
  union { unsigned u; float f; } v;
  v.u = ((unsigned)u) << 16;
  return v.f;
}

// fast gelu: logistic form of tanh-approx; |err vs erf-gelu| <= ~3e-4
__device__ __forceinline__ float gelu_fast(float x) {
  const float y2 = -1.5957691216057308f * x * fmaf(0.044715f, x * x, 1.0f);
  return x * __builtin_amdgcn_rcpf(1.0f + __expf(y2));
}

__device__ __forceinline__ void async16(void* lds, const void* g) {
  auto* lp = (__attribute__((address_space(3))) uint32_t*)lds;
  auto* gp = (__attribute__((address_space(1))) uint32_t*)(const_cast<void*>(g));
  __builtin_amdgcn_global_load_lds(gp, lp, 16, 0, 0);
}

// ---- router v4: FROZEN sequential fmaf chain + fused X16 cast --------------
__global__ __launch_bounds__(256) void router_seq3(
    const float* __restrict__ tokens, const float* __restrict__ rw,
    int* __restrict__ topi, float* __restrict__ topv,
    ushort_t* __restrict__ x16) {
  __shared__ float xs[2][32][132];
  __shared__ float wsh[2][8][132];
  __shared__ float sc[256];
  const int tid = threadIdx.x;
  const int e = tid & 7;
  const int tr = tid >> 3;
  const int t0 = blockIdx.x * 32;

  float4 lx0, lx1, lx2, lx3, lw;
  auto issue = [&](int c) {
    const int col = (tid & 31) * 4;
    lx0 = *(const float4*)&tokens[(size_t)(t0 + ((tid + 0) >> 5)) * DIM + c * 128 + col];
    lx1 = *(const float4*)&tokens[(size_t)(t0 + ((tid + 256) >> 5)) * DIM + c * 128 + col];
    lx2 = *(const float4*)&tokens[(size_t)(t0 + ((tid + 512) >> 5)) * DIM + c * 128 + col];
    lx3 = *(const float4*)&tokens[(size_t)(t0 + ((tid + 768) >> 5)) * DIM + c * 128 + col];
    lw  = *(const float4*)&rw[(size_t)(tid >> 5) * DIM + c * 128 + col];
  };
  auto commit = [&](int b) {
    const int col = (tid & 31) * 4;
    *(float4*)&xs[b][(tid + 0) >> 5][col] = lx0;
    *(float4*)&xs[b][(tid + 256) >> 5][col] = lx1;
    *(float4*)&xs[b][(tid + 512) >> 5][col] = lx2;
    *(float4*)&xs[b][(tid + 768) >> 5][col] = lx3;
    *(float4*)&wsh[b][tid >> 5][col] = lw;
  };
  auto commitX = [&](int c) { // fused tokens->bf16 (same RNE as cast_tokens)
    const int col = c * 128 + (tid & 31) * 4;
    u16x4 u;
    u[0] = f2b(lx0.x); u[1] = f2b(lx0.y); u[2] = f2b(lx0.z); u[3] = f2b(lx0.w);
    *(u16x4*)&x16[(size_t)(t0 + ((tid + 0) >> 5)) * DIM + col] = u;
    u[0] = f2b(lx1.x); u[1] = f2b(lx1.y); u[2] = f2b(lx1.z); u[3] = f2b(lx1.w);
    *(u16x4*)&x16[(size_t)(t0 + ((tid + 256) >> 5)) * DIM + col] = u;
    u[0] = f2b(lx2.x); u[1] = f2b(lx2.y); u[2] = f2b(lx2.z); u[3] = f2b(lx2.w);
    *(u16x4*)&x16[(size_t)(t0 + ((tid + 512) >> 5)) * DIM + col] = u;
    u[0] = f2b(lx3.x); u[1] = f2b(lx3.y); u[2] = f2b(lx3.z); u[3] = f2b(lx3.w);
    *(u16x4*)&x16[(size_t)(t0 + ((tid + 768) >> 5)) * DIM + col] = u;
  };

  issue(0);
  commit(0);
  commitX(0);
  __syncthreads();
  float s = 0.f;
  for (int c = 0; c < 8; c++) {
    const int b = c & 1;
    if (c + 1 < 8) issue(c + 1);
#pragma unroll
    for (int k4 = 0; k4 < 32; k4++) {
      const float4 xv = *(const float4*)&xs[b][tr][k4 * 4];
      const float4 wv = *(const float4*)&wsh[b][e][k4 * 4];
      s = fmaf(xv.x, wv.x, s);
      s = fmaf(xv.y, wv.y, s);
      s = fmaf(xv.z, wv.z, s);
      s = fmaf(xv.w, wv.w, s);
    }
    if (c + 1 < 8) {
      commit(b ^ 1);
      commitX(c + 1);
    }
    __syncthreads();
  }
  sc[tid] = s;
  __syncthreads();
  if (e == 0) {
    float p[NE];
    float m = sc[tr * 8];
#pragma unroll
    for (int i = 1; i < NE; i++) m = fmaxf(m, sc[tr * 8 + i]);
    float sum = 0.f;
#pragma unroll
    for (int i = 0; i < NE; i++) {
      p[i] = expf(sc[tr * 8 + i] - m);
      sum += p[i];
    }
#pragma unroll
    for (int i = 0; i < NE; i++) p[i] = p[i] / sum;
    const int t = t0 + tr;
    int e0 = 0;
#pragma unroll
    for (int i = 1; i < NE; i++) if (p[i] > p[e0]) e0 = i;
    int e1 = (e0 == 0) ? 1 : 0;
#pragma unroll
    for (int i = 0; i < NE; i++) if (i != e0 && p[i] > p[e1]) e1 = i;
    topi[t * 2] = e0;     topv[t * 2] = p[e0];
    topi[t * 2 + 1] = e1; topv[t * 2 + 1] = p[e1];
  }
}

// ---- per-(k,expert) counts -------------------------------------------------
__global__ __launch_bounds__(256) void hist_kernel(const int* __restrict__ topi,
                                                   int* __restrict__ ctrl) {
  __shared__ int h[NSEG];
  const int tid = threadIdx.x;
  if (tid < NSEG) h[tid] = 0;
  __syncthreads();
  const int t = blockIdx.x * 256 + tid;
  atomicAdd(&h[topi[t * 2]], 1);
  atomicAdd(&h[8 + topi[t * 2 + 1]], 1);
  __syncthreads();
  if (tid < NSEG) atomicAdd(&ctrl[C_CNT(tid)], h[tid]);
}

__global__ void prefix_kernel(int* ctrl) {
  if (threadIdx.x == 0 && blockIdx.x == 0) {
    int s = 0;
    for (int g = 0; g < NSEG; g++) {
      ctrl[C_SEG(g)] = s;
      ctrl[C_CUR(g)] = s;
      s += (ctrl[C_CNT(g)] + 255) & ~255; /* pad segments to 256 (BM) */
    }
    ctrl[C_SEG(NSEG)] = s;
  }
}

__global__ __launch_bounds__(256) void init_rows(int* __restrict__ row_token) {
  const int i = blockIdx.x * 256 + threadIdx.x;
  if (i < BMCAP) row_token[i] = TOK;
}

// ---- assign: slot scatter + inverse map (token -> slot) --------------------
__global__ __launch_bounds__(256) void assign2(
    const int* __restrict__ topi, int* __restrict__ ctrl,
    int* __restrict__ row_token, int* __restrict__ inv) {
  __shared__ int h[NSEG];
  __shared__ int base[NSEG];
  const int tid = threadIdx.x;
  const int t = blockIdx.x * 256 + tid;
  if (tid < NSEG) h[tid] = 0;
  __syncthreads();
  const int s0 = topi[t * 2], s1 = 8 + topi[t * 2 + 1];
  const int o0 = atomicAdd(&h[s0], 1);
  const int o1 = atomicAdd(&h[s1], 1);
  __syncthreads();
  if (tid < NSEG) base[tid] = atomicAdd(&ctrl[C_CUR(tid)], h[tid]);
  __syncthreads();
  const int p0 = base[s0] + o0, p1 = base[s1] + o1;
  row_token[p0] = t; inv[t * 2] = p0;
  row_token[p1] = t; inv[t * 2 + 1] = p1;
}

__global__ __launch_bounds__(256) void transpose_cast(
    const float* __restrict__ w, ushort_t* __restrict__ wT) {
  __shared__ float tile[64][65];
  const int e = blockIdx.z;
  const int n0 = blockIdx.x * 64, k0 = blockIdx.y * 64;
  const int tx = threadIdx.x & 63, ty = threadIdx.x >> 6;
  const float* src = w + ((size_t)e << 20);
  ushort_t* dst = wT + ((size_t)e << 20);
#pragma unroll
  for (int r = ty; r < 64; r += 4)
    tile[r][tx] = src[(size_t)(k0 + r) * DIM + n0 + tx];
  __syncthreads();
#pragma unroll
  for (int r = ty; r < 64; r += 4)
    dst[(size_t)(n0 + r) * DIM + k0 + tx] = f2b(tile[tx][r]);
}

// ---- combine: out[t] = g0*gY[slot0] + g1*gY[slot1]  (coalesced, f32) -------
__global__ __launch_bounds__(256) void combine(
    const ushort_t* __restrict__ gY, const int* __restrict__ inv,
    const float* __restrict__ topv, float* __restrict__ out) {
  const size_t i = (size_t)blockIdx.x * 256 + threadIdx.x;
  const int t = (int)(i >> 7);
  const int c = (int)(i & 127) << 3;
  const int s0 = inv[t * 2], s1 = inv[t * 2 + 1];
  const float g0 = topv[t * 2], g1 = topv[t * 2 + 1];
  const bf16x8 y0 = *(const bf16x8*)&gY[(size_t)s0 * DIM + c];
  const bf16x8 y1 = *(const bf16x8*)&gY[(size_t)s1 * DIM + c];
  f32x4 o0, o1;
#pragma unroll
  for (int j = 0; j < 4; j++)
    o0[j] = g0 * b2f((unsigned short)y0[j]) + g1 * b2f((unsigned short)y1[j]);
#pragma unroll
  for (int j = 0; j < 4; j++)
    o1[j] = g0 * b2f((unsigned short)y0[4 + j]) +
            g1 * b2f((unsigned short)y1[4 + j]);
  float* op = out + (size_t)t * DIM + c;
  *(f32x4*)op = o0;
  *(f32x4*)(op + 4) = o1;
}

// --- grouped GEMM: 256x128 tile, BK=32, 8 waves, dbuf, 2 blocks/CU ----------
// r22-VERIFIED shape (207us, VGPR 56, MfmaUtil 30%). r23's 4-wave 64x128
// reshape halved waves/CU (39.6->19.6% occ) and regressed — keep this one.
// launch_bounds(512,4): do NOT raise (r20: (512,6) spilled acc, 3.2x slow).
// PASS 0: H[rr,:]  = gelu(X16[row_token[rr],:] @ w1T[e]^T)   (bf16 rows)
// PASS 1: gY[rr,:] =       H[rr,:]             @ w2T[e]^T    (bf16 rows)
// Both epilogues coalesced slot-row stores; gate applied later in combine.
template <int PASS>
__global__ __launch_bounds__(512, 4) void dgemm(
    const ushort_t* __restrict__ Asrc, const ushort_t* __restrict__ Wt,
    const int* __restrict__ row_token, const int* __restrict__ ctrl, int s_lo,
    int s_hi, int chunk, ushort_t* __restrict__ Hout) {
  const int l = (blockIdx.x & 7) * chunk + (blockIdx.x >> 3);
  const int mt = l >> 3, nt = l & 7; // n-fastest: 8 blocks share an A-panel
  const int rbase0 = ctrl[C_SEG(s_lo)];
  const int rend = ctrl[C_SEG(s_hi)];
  const int m0 = rbase0 + mt * 256;
  if (m0 >= rend) return;
  const int n0 = nt * 128;
  int sg = s_lo;
  for (int i = s_lo + 1; i < s_hi; i++)
    if (m0 >= ctrl[C_SEG(i)]) sg = i;
  const int e = sg & 7;
  const ushort_t* B = Wt + ((size_t)e << 20);

  __shared__ __align__(16) char smem[49152];
  ushort_t (*As)[8192] = (ushort_t(*)[8192])smem;           // 2 x 16 KB
  ushort_t (*Bs)[4096] = (ushort_t(*)[4096])(smem + 32768); // 2 x 8 KB
  float* scratch = (float*)smem; // epilogue: 64x128 f32 = 32 KB

  const int tid = threadIdx.x;
  const int lane = tid & 63;
  const int wave = tid >> 6;
  const int wm = wave >> 1, wn = wave & 1; // per-wave 64x64 output
  const int lr = lane & 15;
  const int kx = (((lane >> 4) ^ (lr & 3) ^ ((lr >> 2) & 3)) << 3);

  const int ko = (((lane & 3) ^ ((lane >> 2) & 3) ^ ((lane >> 4) & 3)) << 3);
  const int ar0 = wave * 32 + (lane >> 2);
  const int brr = wave * 16 + (lane >> 2);
  const ushort_t *asrc0, *asrc1, *bsrc;
  if (PASS == 0) {
    int tk0 = row_token[m0 + ar0];
    int tk1 = row_token[m0 + ar0 + 16];
    if (tk0 >= TOK) tk0 = 0;
    if (tk1 >= TOK) tk1 = 0;
    asrc0 = Asrc + (size_t)tk0 * DIM + ko;
    asrc1 = Asrc + (size_t)tk1 * DIM + ko;
  } else {
    asrc0 = Asrc + (size_t)(m0 + ar0) * DIM + ko;
    asrc1 = Asrc + (size_t)(m0 + ar0 + 16) * DIM + ko;
  }
  bsrc = B + (size_t)(n0 + brr) * DIM + ko;

  f32x4 acc[4][4] = {};

  auto stage = [&](int b, int k0) {
    async16(&As[b][wave * 1024], asrc0 + k0);
    async16(&As[b][wave * 1024 + 512], asrc1 + k0);
    async16(&Bs[b][wave * 512], bsrc + k0);
  };
  auto compute = [&](int b) {
    bf16x8 a[4], bb[4];
#pragma unroll
    for (int mi = 0; mi < 4; mi++)
      a[mi] = *(const bf16x8*)&As[b][(wm * 64 + mi * 16 + lr) * 32 + kx];
#pragma unroll
    for (int ni = 0; ni < 4; ni++)
      bb[ni] = *(const bf16x8*)&Bs[b][(wn * 64 + ni * 16 + lr) * 32 + kx];
#pragma unroll
    for (int mi = 0; mi < 4; mi++)
#pragma unroll
      for (int ni = 0; ni < 4; ni++)
        acc[mi][ni] = __builtin_amdgcn_mfma_f32_16x16x32_bf16(
            a[mi], bb[ni], acc[mi][ni], 0, 0, 0);
  };

  stage(0, 0);
  __syncthreads();
  int cur = 0;
#pragma unroll 1
  for (int t = 0; t < 31; t++) {
    stage(cur ^ 1, (t + 1) * 32);
    compute(cur);
    __syncthreads();
    cur ^= 1;
  }
  compute(cur);
  __syncthreads(); // K-loop done; smem becomes scratch

  // ---- epilogue: 4 rounds (one 64-row m-block each), coalesced stores -----
  const int grow = (lane >> 4) << 2;
  const int erow = tid >> 3;       // 0..63
  const int ec0 = (tid & 7) * 16;  // col base, 16 cols/thread
#pragma unroll 1
  for (int rnd = 0; rnd < 4; rnd++) {
    if (wm == rnd) {
#pragma unroll
      for (int mi = 0; mi < 4; mi++) {
#pragma unroll
        for (int ni = 0; ni < 4; ni++) {
#pragma unroll
          for (int r = 0; r < 4; r++) {
            const int lrow = mi * 16 + grow + r;
            const int lcol = (wn * 64 + ni * 16 + lr) ^ ((lrow & 3) << 2);
            scratch[lrow * 128 + lcol] = acc[mi][ni][r];
          }
        }
      }
    }
    __syncthreads();
    {
      const int q = (erow & 3) << 2;
      f32x4 v[4];
#pragma unroll
      for (int k = 0; k < 4; k++)
        v[k] = *(const f32x4*)&scratch[erow * 128 + ((ec0 + 4 * k) ^ q)];
      const int rr = m0 + rnd * 64 + erow;
      bf16x8 h0, h1;
      if (PASS == 0) {
#pragma unroll
        for (int k = 0; k < 2; k++)
#pragma unroll
          for (int j = 0; j < 4; j++)
            h0[k * 4 + j] = (short)f2b(gelu_fast(v[k][j]));
#pragma unroll
        for (int k = 0; k < 2; k++)
#pragma unroll
          for (int j = 0; j < 4; j++)
            h1[k * 4 + j] = (short)f2b(gelu_fast(v[2 + k][j]));
      } else {
#pragma unroll
        for (int k = 0; k < 2; k++)
#pragma unroll
          for (int j = 0; j < 4; j++) h0[k * 4 + j] = (short)f2b(v[k][j]);
#pragma unroll
        for (int k = 0; k < 2; k++)
#pragma unroll
          for (int j = 0; j < 4; j++) h1[k * 4 + j] = (short)f2b(v[2 + k][j]);
      }
      *(bf16x8*)&Hout[(size_t)rr * DIM + n0 + ec0] = h0;
      *(bf16x8*)&Hout[(size_t)rr * DIM + n0 + ec0 + 8] = h1;
    }
    __syncthreads();
  }
}

extern "C" void kernel_launch(void* const* d_in, const int* in_sizes, int n_in,
                              void* d_out, int out_size, void* d_ws,
                              size_t ws_size, hipStream_t stream) {
  (void)in_sizes; (void)n_in; (void)ws_size; (void)out_size;
  const float* tokens = (const float*)d_in[0];
  const float* rw = (const float*)d_in[1];
  const float* w1 = (const float*)d_in[2];
  const float* w2 = (const float*)d_in[3];
  float* out = (float*)d_out;

  char* ws = (char*)d_ws;
  size_t off = 0;
  auto alloc = [&](size_t b) {
    size_t o = off;
    off += (b + 255) & ~(size_t)255;
    return o;
  };
  int* ctrl = (int*)(ws + alloc(4096));
  int* topi = (int*)(ws + alloc((size_t)TOK * 2 * 4));
  float* topv = (float*)(ws + alloc((size_t)TOK * 2 * 4));
  int* inv = (int*)(ws + alloc((size_t)TOK * 2 * 4));
  int* row_token = (int*)(ws + alloc((size_t)BMCAP * 4));
  ushort_t* w2T = (ushort_t*)(ws + alloc((size_t)NE * DIM * DIM * 2));
  ushort_t* H = (ushort_t*)(ws + alloc((size_t)BMCAP * DIM * 2));
  // region: X16 + w1T (pass-0 only) overlaid by gY (pass-1 output)
  const size_t region = alloc((size_t)BMCAP * DIM * 2); // 142.6 MB
  ushort_t* X16 = (ushort_t*)(ws + region);                         // 67 MB
  ushort_t* w1T = (ushort_t*)(ws + region + (size_t)TOK * DIM * 2); // 16.8 MB
  ushort_t* gY = (ushort_t*)(ws + region); // aliases X16+w1T (dead by pass-1)

  hipMemsetAsync(ctrl, 0, 4096, stream);
  router_seq3<<<TOK / 32, 256, 0, stream>>>(tokens, rw, topi, topv, X16);
  hist_kernel<<<TOK / 256, 256, 0, stream>>>(topi, ctrl);
  prefix_kernel<<<1, 64, 0, stream>>>(ctrl);
  init_rows<<<BMCAP / 256, 256, 0, stream>>>(row_token);
  assign2<<<TOK / 256, 256, 0, stream>>>(topi, ctrl, row_token, inv);
  dim3 tg(16, 16, 8);
  transpose_cast<<<tg, 256, 0, stream>>>(w1, w1T);
  transpose_cast<<<tg, 256, 0, stream>>>(w2, w2T);
  // pass-0: all 16 segments -> H (272 m-tiles x 8 n-tiles = 2176 blocks)
  dgemm<0><<<2176, 512, 0, stream>>>(X16, w1T, row_token, ctrl, 0, NSEG, 272,
                                     H);
  // pass-1: all 16 segments -> gY (coalesced, no scatter/atomics/RMW)
  dgemm<1><<<2176, 512, 0, stream>>>(H, w2T, row_token, ctrl, 0, NSEG, 272,
                                     gY);
  // combine: out[t] = g0*gY[slot0] + g1*gY[slot1]
  combine<<<TOK * (DIM / 8) / 256, 256, 0, stream>>>(gY, inv, topv, out);
}